// Round 10
// baseline (4303.472 us; speedup 1.0000x reference)
//
#include <hip/hip_runtime.h>
#include <stdint.h>

typedef unsigned int u32;
typedef unsigned short u16;
typedef unsigned char u8;
typedef __attribute__((ext_vector_type(8))) short s8v;
typedef __attribute__((ext_vector_type(8))) __bf16 bf16x8;
typedef __attribute__((ext_vector_type(4))) float f32x4;

// ---------------- workspace layout (bytes) ----------------
#define OFF_HENC 0ull                 // [16][96][256][128] bf16 (raw h, pre-LN)
#define OFF_M    100663296ull         // [16][96][256][128] bf16 (intermediate)
#define OFF_MI8  201326592ull         // [1536][256][128] u8   (50331648)
#define OFF_MSCL 251658240ull         // [1536][256] f32       (1572864)
#define OFF_APF  253231104ull         // [4][96][96] f32
#define OFF_APB  253378560ull         // [4][96][96] bf16
#define OFF_WNF  253452288ull         // [8*5][64][8] bf16
#define OFF_WSF  253493248ull         // [8*5][64][8] bf16
#define OFF_KWF  253534208ull         // [8*4][64][8] bf16
#define OFF_VWF  253566976ull         // [8*4][64][8] bf16
#define OFF_WIHF 253599744ull         // [24*4][64][8] bf16
#define OFF_WHHF 253698048ull         // [24*4][64][8] bf16
#define OFF_CWY  253796352ull         // [384][4] f32
#define OFF_UPAD 253802496ull         // [256][32] bf16
#define OFF_SCAL 253818880ull         // scal[0]=1/sigma, scal[1]=exp(log_tau)
#define OFF_HH   253819136ull         // [1536][128] f32 head h0
#define OFF_Y    254605568ull         // 2 x [1536][4] f32 ping-pong y
#define OFF_BAR  254654720ull         // int cnt[16], gen[16]

__device__ __forceinline__ u16 f2bf(float f) {
  u32 u = __float_as_uint(f);
  u32 r = u + 0x7fffu + ((u >> 16) & 1u);
  return (u16)(r >> 16);
}
__device__ __forceinline__ float bf2f(u16 h) { return __uint_as_float(((u32)h) << 16); }
__device__ __forceinline__ float blo(u32 u) { return __uint_as_float(u << 16); }
__device__ __forceinline__ float bhi(u32 u) { return __uint_as_float(u & 0xffff0000u); }
__device__ __forceinline__ float sigm(float x) { return 1.f / (1.f + __expf(-x)); }
__device__ __forceinline__ float tanh_f(float x) {
  float a = fminf(fabsf(x), 15.f);
  float e = __expf(2.f * a);
  float t = (e - 1.f) / (e + 1.f);
  return copysignf(t, x);
}
__device__ __forceinline__ f32x4 MFMA(s8v a, s8v b, f32x4 c) {
  return __builtin_amdgcn_mfma_f32_16x16x32_bf16(
      __builtin_bit_cast(bf16x8, a), __builtin_bit_cast(bf16x8, b), c, 0, 0, 0);
}
__device__ __forceinline__ float ub0(u32 x) { return (float)(x & 0xffu); }
__device__ __forceinline__ float ub1(u32 x) { return (float)((x >> 8) & 0xffu); }
__device__ __forceinline__ float ub2(u32 x) { return (float)((x >> 16) & 0xffu); }
__device__ __forceinline__ float ub3(u32 x) { return (float)((x >> 24) & 0xffu); }

// =====================================================================
// K0a
// =====================================================================
__global__ void k0a(const float* __restrict__ S, const float* __restrict__ G,
                    const float* __restrict__ Wn, const float* __restrict__ snu,
                    const float* __restrict__ logtau, const float* __restrict__ tpw,
                    const float* __restrict__ tpb, const float* __restrict__ cWih,
                    float* __restrict__ Apf, u16* __restrict__ Apb,
                    float* __restrict__ scal, u16* __restrict__ upad,
                    float* __restrict__ cWy) {
  int tid = threadIdx.x;
  int blk = blockIdx.x;
  if (blk < 4) {
    int p = blk;
    __shared__ float gg[96];
    __shared__ float gfac;
    if (tid < 96) {
      float x = G[p * 96 + tid];
      float sp = fmaxf(x, 0.f) + log1pf(__expf(-fabsf(x)));
      gg[tid] = sp + 1e-6f;
    }
    __syncthreads();
    if (tid == 0) {
      float s = 0;
      for (int i = 0; i < 96; ++i) s += gg[i];
      gfac = 96.f / fmaxf(s, 1e-6f);
    }
    __syncthreads();
    if (tid < 96) {
      int i = tid;
      const float* srow = S + ((size_t)p * 96 + i) * 96;
      float den = 0;
      for (int j = 0; j < 96; ++j) { float v = (j == i) ? 0.f : srow[j]; den += fabsf(v); }
      den = fmaxf(den, 1e-6f);
      float sc = gg[i] * gfac / den;
      for (int j = 0; j < 96; ++j) {
        float v = (j == i) ? 0.f : srow[j];
        float a = v * sc;
        Apf[((size_t)p * 96 + i) * 96 + j] = a;
        Apb[((size_t)p * 96 + i) * 96 + j] = f2bf(a);
      }
    }
  } else if (blk == 4) {
    __shared__ float sv[144];
    __shared__ float su[128];
    __shared__ float snorm;
    if (tid < 144) {
      float a = 0;
      for (int d = 0; d < 128; ++d) a += Wn[d * 144 + tid] * snu[d];
      sv[tid] = a;
    }
    __syncthreads();
    if (tid == 0) {
      float s = 0;
      for (int j = 0; j < 144; ++j) s += sv[j] * sv[j];
      snorm = sqrtf(s) + 1e-12f;
    }
    __syncthreads();
    if (tid < 144) sv[tid] = sv[tid] / snorm;
    __syncthreads();
    if (tid < 128) {
      float a = 0;
      for (int j = 0; j < 144; ++j) a += Wn[tid * 144 + j] * sv[j];
      su[tid] = a;
    }
    __syncthreads();
    if (tid == 0) {
      float ss = 0;
      for (int d = 0; d < 128; ++d) ss += su[d] * su[d];
      float nu = sqrtf(ss);
      float sigma = ss / (nu + 1e-12f);
      scal[0] = 1.f / sigma;
      scal[1] = __expf(logtau[0]);
    }
  } else {
    for (int idx = tid; idx < 256 * 32; idx += 256) {
      int t = idx >> 5, kk = idx & 31;
      float v = 0.f;
      if (kk < 16) v = tanh_f((float)t * (1.f / 255.f) * tpw[kk] + tpb[kk]);
      upad[idx] = f2bf(v);
    }
    for (int idx = tid; idx < 1536; idx += 256)
      cWy[idx] = cWih[(idx >> 2) * 132 + 128 + (idx & 3)];
  }
}

// =====================================================================
// K0b
// =====================================================================
__global__ void k0b(const float* __restrict__ Wn, const float* __restrict__ Ws,
                    const float* __restrict__ kw, const float* __restrict__ vw,
                    const float* __restrict__ cWih, const float* __restrict__ cWhh,
                    const float* __restrict__ scal,
                    u16* __restrict__ WnF, u16* __restrict__ WsF,
                    u16* __restrict__ kwF, u16* __restrict__ vwF,
                    u16* __restrict__ wiF, u16* __restrict__ whF) {
  int idx = blockIdx.x * 256 + threadIdx.x;
  int lane, j, ctkq, ct, kq, col, k;
  if (idx < 20480) {
    ctkq = idx >> 9; lane = (idx >> 3) & 63; j = idx & 7;
    ct = ctkq / 5; kq = ctkq % 5;
    col = ct * 16 + (lane & 15); k = kq * 32 + ((lane >> 4) << 3) + j;
    float v = (k < 144) ? Wn[col * 144 + k] * scal[0] : 0.f;
    WnF[idx] = f2bf(v);
    return;
  }
  idx -= 20480;
  if (idx < 20480) {
    ctkq = idx >> 9; lane = (idx >> 3) & 63; j = idx & 7;
    ct = ctkq / 5; kq = ctkq % 5;
    col = ct * 16 + (lane & 15); k = kq * 32 + ((lane >> 4) << 3) + j;
    float v = (k < 144) ? Ws[col * 144 + k] : 0.f;
    WsF[idx] = f2bf(v);
    return;
  }
  idx -= 20480;
  if (idx < 16384) {
    ctkq = idx >> 9; lane = (idx >> 3) & 63; j = idx & 7;
    ct = ctkq >> 2; kq = ctkq & 3;
    col = ct * 16 + (lane & 15); k = kq * 32 + ((lane >> 4) << 3) + j;
    kwF[idx] = f2bf(kw[k * 128 + col]);
    return;
  }
  idx -= 16384;
  if (idx < 16384) {
    ctkq = idx >> 9; lane = (idx >> 3) & 63; j = idx & 7;
    ct = ctkq >> 2; kq = ctkq & 3;
    col = ct * 16 + (lane & 15); k = kq * 32 + ((lane >> 4) << 3) + j;
    vwF[idx] = f2bf(vw[col * 128 + k]);
    return;
  }
  idx -= 16384;
  if (idx < 49152) {
    ctkq = idx >> 9; lane = (idx >> 3) & 63; j = idx & 7;
    ct = ctkq >> 2; kq = ctkq & 3;
    col = ct * 16 + (lane & 15); k = kq * 32 + ((lane >> 4) << 3) + j;
    wiF[idx] = f2bf(cWih[col * 132 + k]);
    return;
  }
  idx -= 49152;
  if (idx < 49152) {
    ctkq = idx >> 9; lane = (idx >> 3) & 63; j = idx & 7;
    ct = ctkq >> 2; kq = ctkq & 3;
    col = ct * 16 + (lane & 15); k = kq * 32 + ((lane >> 4) << 3) + j;
    whF[idx] = f2bf(cWhh[col * 128 + k]);
  }
}

// =====================================================================
// K1: GRU encode, LN deferred to k3. One block per n, 8 waves.
// =====================================================================
__launch_bounds__(512)
__global__ void k1_encode(const float* __restrict__ X, const float* __restrict__ Wih,
                          const float* __restrict__ Whh, const float* __restrict__ bih,
                          const float* __restrict__ bhh, u16* __restrict__ Henc) {
  const int n = blockIdx.x;
  const int lane = threadIdx.x & 63, w = threadIdx.x >> 6;
  const int colt = lane & 15, grp = lane >> 4;
  __shared__ __align__(16) float Xl[16][256][4];
  __shared__ __align__(16) u16 hb[2][16][136];

  for (int idx = threadIdx.x; idx < 16 * 1024; idx += 512) {
    int b = idx >> 10, rem = idx & 1023, c = rem >> 8, t = rem & 255;
    Xl[b][t][c] = X[(((size_t)b * 96 + n) * 4 + c) * 256 + t];
  }
  for (int idx = threadIdx.x; idx < 2 * 16 * 136; idx += 512) (&hb[0][0][0])[idx] = 0;

  s8v bfr[3][4];
#pragma unroll
  for (int g = 0; g < 3; ++g) {
    int col = g * 128 + w * 16 + colt;
    const float* wr = Whh + ((size_t)n * 384 + col) * 128;
#pragma unroll
    for (int kq = 0; kq < 4; ++kq) {
      int k0 = kq * 32 + grp * 8;
      float4 f0 = *(const float4*)(wr + k0);
      float4 f1 = *(const float4*)(wr + k0 + 4);
      union { s8v v; u16 s[8]; } tmp;
      tmp.s[0] = f2bf(f0.x); tmp.s[1] = f2bf(f0.y); tmp.s[2] = f2bf(f0.z); tmp.s[3] = f2bf(f0.w);
      tmp.s[4] = f2bf(f1.x); tmp.s[5] = f2bf(f1.y); tmp.s[6] = f2bf(f1.z); tmp.s[7] = f2bf(f1.w);
      bfr[g][kq] = tmp.v;
    }
  }
  float wihr[3][4], bi[3], bh[3];
#pragma unroll
  for (int g = 0; g < 3; ++g) {
    int col = g * 128 + w * 16 + colt;
    float4 wv = *(const float4*)(Wih + ((size_t)n * 384 + col) * 4);
    wihr[g][0] = wv.x; wihr[g][1] = wv.y; wihr[g][2] = wv.z; wihr[g][3] = wv.w;
    bi[g] = bih[n * 384 + col];
    bh[g] = bhh[n * 384 + col];
  }
  float h_reg[4] = {0.f, 0.f, 0.f, 0.f};
  __syncthreads();

  int cur = 0;
  for (int t = 0; t < 256; ++t) {
    s8v a[4];
#pragma unroll
    for (int kq = 0; kq < 4; ++kq)
      a[kq] = *(const s8v*)(const void*)&hb[cur][colt][kq * 32 + grp * 8];
    f32x4 acc0 = {0.f, 0.f, 0.f, 0.f}, acc1 = acc0, acc2 = acc0;
#pragma unroll
    for (int kq = 0; kq < 4; ++kq) {
      acc0 = MFMA(a[kq], bfr[0][kq], acc0);
      acc1 = MFMA(a[kq], bfr[1][kq], acc1);
      acc2 = MFMA(a[kq], bfr[2][kq], acc2);
    }
#pragma unroll
    for (int r = 0; r < 4; ++r) {
      int b = grp * 4 + r;
      float4 x4 = *(const float4*)&Xl[b][t][0];
      float gir = bi[0] + x4.x * wihr[0][0] + x4.y * wihr[0][1] + x4.z * wihr[0][2] + x4.w * wihr[0][3];
      float giz = bi[1] + x4.x * wihr[1][0] + x4.y * wihr[1][1] + x4.z * wihr[1][2] + x4.w * wihr[1][3];
      float gin = bi[2] + x4.x * wihr[2][0] + x4.y * wihr[2][1] + x4.z * wihr[2][2] + x4.w * wihr[2][3];
      float rr = sigm(gir + acc0[r] + bh[0]);
      float zz = sigm(giz + acc1[r] + bh[1]);
      float nn = tanh_f(gin + rr * (acc2[r] + bh[2]));
      float hv = (1.f - zz) * nn + zz * h_reg[r];
      h_reg[r] = hv;
      u16 hvb = f2bf(hv);
      Henc[(((size_t)b * 96 + n) * 256 + t) * 128 + w * 16 + colt] = hvb;
      hb[cur ^ 1][b][w * 16 + colt] = hvb;
    }
    __syncthreads();
    cur ^= 1;
  }
}

// =====================================================================
// K3: per (b,t): LN -> Hc, Hn = Wsn@Hc, Zn = A@Hn, Hs = Wself@Hc,
// Z = leaky(Hs+Zn) -> M (bf16); at t=255 also h0 -> hh.
// =====================================================================
__launch_bounds__(256, 2)
__global__ void k3_mix(const u16* __restrict__ Henc, const u16* __restrict__ upad,
                       const u16* __restrict__ Apb, const int* __restrict__ phases,
                       const float* __restrict__ lng, const float* __restrict__ lnb,
                       const s8v* __restrict__ WnF, const s8v* __restrict__ WsF,
                       u16* __restrict__ M, float* __restrict__ hh) {
  const int b = blockIdx.x >> 8, t = blockIdx.x & 255;
  const int p = phases[b];
  const int lane = threadIdx.x & 63, w = threadIdx.x >> 6;
  const int colt = lane & 15, grp = lane >> 4;
  __shared__ __align__(16) u16 Hc[96][168];
  __shared__ __align__(16) u16 HnT[128][104];
  __shared__ float lnG[128], lnB[128];

  const u16* src = Henc + ((size_t)b * 96 * 256 + t) * 128;
  for (int u = threadIdx.x; u < 96 * 16; u += 256) {
    int j = u >> 4, ch = u & 15;
    *(uint4*)&Hc[j][ch * 8] = *(const uint4*)(src + (size_t)j * 256 * 128 + ch * 8);
  }
  for (int u = threadIdx.x; u < 96 * 16; u += 256) {
    int j = u >> 4, ch = u & 15;
    *(u32*)&Hc[j][128 + ch * 2] = *(const u32*)(upad + t * 32 + ch * 2);
  }
  if (threadIdx.x < 128) {
    lnG[threadIdx.x] = lng[threadIdx.x];
    lnB[threadIdx.x] = lnb[threadIdx.x];
  }
  __syncthreads();
  if (threadIdx.x < 96) {
    int j = threadIdx.x;
    float s = 0.f, q = 0.f;
#pragma unroll 4
    for (int d = 0; d < 128; ++d) {
      float v = bf2f(Hc[j][d]);
      s += v; q += v * v;
    }
    float mu = s * (1.f / 128.f);
    float var = q * (1.f / 128.f) - mu * mu;
    float rs = rsqrtf(var + 1e-5f);
#pragma unroll 4
    for (int d = 0; d < 128; ++d) {
      float v = bf2f(Hc[j][d]);
      Hc[j][d] = f2bf((v - mu) * rs * lnG[d] + lnB[d]);
    }
  }
  __syncthreads();
  for (int jj = 0; jj < 12; ++jj) {
    int job = w * 12 + jj;
    int jt = job >> 3, ct = job & 7;
    f32x4 acc = {0.f, 0.f, 0.f, 0.f};
#pragma unroll
    for (int kq = 0; kq < 5; ++kq) {
      s8v a = *(const s8v*)(const void*)&Hc[jt * 16 + colt][kq * 32 + grp * 8];
      acc = MFMA(a, WnF[(ct * 5 + kq) * 64 + lane], acc);
    }
    int d = ct * 16 + colt, j0 = jt * 16 + grp * 4;
    u32 w0 = ((u32)f2bf(acc[1]) << 16) | f2bf(acc[0]);
    u32 w1 = ((u32)f2bf(acc[3]) << 16) | f2bf(acc[2]);
    *(u32*)&HnT[d][j0] = w0;
    *(u32*)&HnT[d][j0 + 2] = w1;
  }
  __syncthreads();
  for (int jj = 0; jj < 12; ++jj) {
    int job = w * 12 + jj;
    int it = job >> 3, ct = job & 7;
    f32x4 accZ = {0.f, 0.f, 0.f, 0.f}, accS = accZ;
#pragma unroll
    for (int kq = 0; kq < 3; ++kq) {
      s8v a = *(const s8v*)(const void*)(Apb + ((size_t)p * 96 + it * 16 + colt) * 96 + kq * 32 + grp * 8);
      s8v bb = *(const s8v*)(const void*)&HnT[ct * 16 + colt][kq * 32 + grp * 8];
      accZ = MFMA(a, bb, accZ);
    }
#pragma unroll
    for (int kq = 0; kq < 5; ++kq) {
      s8v a = *(const s8v*)(const void*)&Hc[it * 16 + colt][kq * 32 + grp * 8];
      accS = MFMA(a, WsF[(ct * 5 + kq) * 64 + lane], accS);
    }
    int d = ct * 16 + colt;
#pragma unroll
    for (int r = 0; r < 4; ++r) {
      int i = it * 16 + grp * 4 + r;
      float z = accS[r] + accZ[r];
      z = z >= 0.f ? z : 0.1f * z;
      M[(((size_t)b * 96 + i) * 256 + t) * 128 + d] = f2bf(z);
      if (t == 255) hh[((size_t)b * 96 + i) * 128 + d] = z;
    }
  }
}

// =====================================================================
// K3b: quantize M bf16 -> int8 row-scaled. Block = m (1536), thread = t.
// =====================================================================
__launch_bounds__(256)
__global__ void k3b(const u16* __restrict__ Mbf, u8* __restrict__ Mi8,
                    float* __restrict__ Mscl) {
  const size_t m = blockIdx.x;
  const int t = threadIdx.x;
  const u16* src = Mbf + (m * 256 + t) * 128;
  float vals[128];
  float mx = 0.f;
#pragma unroll 8
  for (int d = 0; d < 128; ++d) {
    float f = bf2f(src[d]);
    vals[d] = f;
    mx = fmaxf(mx, fabsf(f));
  }
  float scale = mx * (1.f / 127.f);
  float inv = (mx > 0.f) ? (127.f / mx) : 0.f;
  u32* dst = (u32*)(Mi8 + (m * 256 + t) * 128);
#pragma unroll 8
  for (int dw = 0; dw < 32; ++dw) {
    u32 packed = 0;
#pragma unroll
    for (int j = 0; j < 4; ++j) {
      int q = (int)rintf(vals[dw * 4 + j] * inv) + 128;
      packed |= ((u32)(q & 0xff)) << (8 * j);
    }
    dst[dw] = packed;
  }
  Mscl[m * 256 + t] = scale;
}

// =====================================================================
// K4P: persistent head, 256 blocks x 512 threads (8 waves, 1 block/CU).
// M int8 chunk in VGPRs: uint2 Mreg[6][8] = 96 VGPR/lane. The mi loop
// in phase C MUST be fully unrolled (rule #20): round 9's `unroll 1`
// made Mreg[mi] runtime-indexed -> scratch -> 1.6 GB FETCH.
// =====================================================================
__device__ __forceinline__ void group_barrier(int* cnt, int* gen) {
  __syncthreads();
  if (threadIdx.x == 0) {
    int g = __hip_atomic_load(gen, __ATOMIC_RELAXED, __HIP_MEMORY_SCOPE_AGENT);
    int v = __hip_atomic_fetch_add(cnt, 1, __ATOMIC_ACQ_REL, __HIP_MEMORY_SCOPE_AGENT);
    if (v == 15) {
      __hip_atomic_store(cnt, 0, __ATOMIC_RELAXED, __HIP_MEMORY_SCOPE_AGENT);
      __hip_atomic_fetch_add(gen, 1, __ATOMIC_ACQ_REL, __HIP_MEMORY_SCOPE_AGENT);
    } else {
      while (__hip_atomic_load(gen, __ATOMIC_ACQUIRE, __HIP_MEMORY_SCOPE_AGENT) == g)
        __builtin_amdgcn_s_sleep(2);
    }
  }
  __syncthreads();
}

__global__ void
__attribute__((amdgpu_flat_work_group_size(512, 512), amdgpu_waves_per_eu(2, 2)))
k4p(const u8* __restrict__ Mi8, const float* __restrict__ Mscl,
    const float* __restrict__ hh,
    float* __restrict__ ybuf, int* __restrict__ bar,
    const float* __restrict__ Apf, const int* __restrict__ phases,
    const float* __restrict__ scal,
    const s8v* __restrict__ kwF, const s8v* __restrict__ vwF,
    const s8v* __restrict__ wiF, const s8v* __restrict__ whF,
    const float* __restrict__ cWy, const float* __restrict__ cbih,
    const float* __restrict__ cbhh, const float* __restrict__ rw,
    const float* __restrict__ rb, const float* __restrict__ X,
    float* __restrict__ out) {
  const int bl = blockIdx.x;
  const int b = bl >> 4, n0 = (bl & 15) * 6, m0 = b * 96 + n0;
  const int lane = threadIdx.x & 63, w = threadIdx.x >> 6;
  const int colt = lane & 15, grp = lane >> 4;
  int* cnt = bar + b;
  int* gen = bar + 16 + b;

  __shared__ float hfl[6][128];
  __shared__ __align__(16) u16 hb[16][136];
  __shared__ __align__(16) u16 qb[6][128];
  __shared__ __align__(16) u16 sb[16][136];
  __shared__ __align__(16) u16 cxb[16][136];
  __shared__ __align__(16) float macc[6][8][128];
  __shared__ float mmd[6][8][3];
  __shared__ float sclL[6][256];
  __shared__ float gi_l[6][392];
  __shared__ float gh_l[6][392];
  __shared__ float ypl[6][4];
  __shared__ float Arows[6][96];
  __shared__ float cbl_i[384], cbl_h[384];
  __shared__ float cWyl[384][4];
  __shared__ float rwl[4][128];
  __shared__ float rbl[4];
  __shared__ float xlast[6][4];

  // ---------------- prologue ----------------
  const int p = phases[b];
  const float scale = scal[1];

  uint2 Mreg[6][8];
#pragma unroll
  for (int mi = 0; mi < 6; ++mi) {
    const u8* base = Mi8 + (((size_t)(m0 + mi) * 256) + w * 32 + grp * 8) * 128 + colt * 8;
#pragma unroll
    for (int r = 0; r < 8; ++r)
      Mreg[mi][r] = *(const uint2*)(base + (size_t)r * 128);
  }

  for (int idx = threadIdx.x; idx < 2048; idx += 512) {
    int i = idx >> 7, d = idx & 127;
    float hv = 0.f;
    if (i < 6) {
      hv = hh[(size_t)(m0 + i) * 128 + d];
      hfl[i][d] = hv;
    } else {
      sb[i][d] = 0;
      cxb[i][d] = 0;
    }
    hb[i][d] = f2bf(hv);
  }
  for (int idx = threadIdx.x; idx < 1536; idx += 512) {
    int mi = idx >> 8, t = idx & 255;
    sclL[mi][t] = Mscl[(size_t)(m0 + mi) * 256 + t];
  }
  for (int idx = threadIdx.x; idx < 576; idx += 512) {
    int i = idx / 96, j = idx % 96;
    Arows[i][j] = Apf[((size_t)p * 96 + (n0 + i)) * 96 + j];
  }
  if (threadIdx.x < 384) {
    cbl_i[threadIdx.x] = cbih[threadIdx.x];
    cbl_h[threadIdx.x] = cbhh[threadIdx.x];
  }
  for (int idx = threadIdx.x; idx < 1536; idx += 512)
    (&cWyl[0][0])[idx] = cWy[idx];
  if (threadIdx.x < 512) (&rwl[0][0])[threadIdx.x] = rw[threadIdx.x];
  if (threadIdx.x < 4) rbl[threadIdx.x] = rb[threadIdx.x];
  if (threadIdx.x < 24)
    xlast[threadIdx.x >> 2][threadIdx.x & 3] =
        X[((size_t)(m0 + (threadIdx.x >> 2)) * 4 + (threadIdx.x & 3)) * 256 + 255];
  __syncthreads();

  // ---------------- 64-step loop ----------------
#pragma unroll 1
  for (int k = 0; k < 64; ++k) {
    const float* yin = ybuf + (size_t)(k & 1) * 6144;
    float* yout = ybuf + (size_t)((k + 1) & 1) * 6144;

    // phase A: y-propagate; wave w<6 handles m=w
    if (w < 6) {
      int mi = w, ni = n0 + w;
      float a0 = 0.f, a1 = 0.f, a2 = 0.f, a3 = 0.f;
#pragma unroll 1
      for (int j = lane; j < 96; j += 64) {
        float av = Arows[mi][j];
        float* yr = (float*)(yin + ((size_t)b * 96 + j) * 4);
        a0 += av * __hip_atomic_load(yr + 0, __ATOMIC_RELAXED, __HIP_MEMORY_SCOPE_AGENT);
        a1 += av * __hip_atomic_load(yr + 1, __ATOMIC_RELAXED, __HIP_MEMORY_SCOPE_AGENT);
        a2 += av * __hip_atomic_load(yr + 2, __ATOMIC_RELAXED, __HIP_MEMORY_SCOPE_AGENT);
        a3 += av * __hip_atomic_load(yr + 3, __ATOMIC_RELAXED, __HIP_MEMORY_SCOPE_AGENT);
      }
#pragma unroll
      for (int mm = 1; mm < 64; mm <<= 1) {
        a0 += __shfl_xor(a0, mm); a1 += __shfl_xor(a1, mm);
        a2 += __shfl_xor(a2, mm); a3 += __shfl_xor(a3, mm);
      }
      if (lane < 4) {
        float av = (lane == 0) ? a0 : (lane == 1) ? a1 : (lane == 2) ? a2 : a3;
        float yo = __hip_atomic_load((float*)(yin + ((size_t)b * 96 + ni) * 4 + lane),
                                     __ATOMIC_RELAXED, __HIP_MEMORY_SCOPE_AGENT);
        ypl[mi][lane] = yo + 0.3f * av;
      }
    }

    // phase B: q = h @ k_w (8 waves, ct = w)
    {
      int ct = w;
      f32x4 acc = {0.f, 0.f, 0.f, 0.f};
#pragma unroll
      for (int kq = 0; kq < 4; ++kq) {
        s8v a = *(const s8v*)(const void*)&hb[colt][kq * 32 + grp * 8];
        acc = MFMA(a, kwF[(ct * 4 + kq) * 64 + lane], acc);
      }
#pragma unroll
      for (int r = 0; r < 4; ++r) {
        int i = grp * 4 + r;
        if (i < 6) qb[i][ct * 16 + colt] = f2bf(acc[r] * scale);
      }
    }
    __syncthreads();

    // phase C: int8 scores+softmax+weighted-sum from REGISTERS.
    // mi loop FULLY unrolled -> all Mreg indexing compile-time (rule #20).
#pragma unroll
    for (int mi = 0; mi < 6; ++mi) {
      float qf[8];
      {
        const u32* qsrc = (const u32*)&qb[mi][colt * 8];
#pragma unroll
        for (int x = 0; x < 4; ++x) {
          u32 v = qsrc[x];
          qf[2 * x] = blo(v); qf[2 * x + 1] = bhi(v);
        }
      }
      float qs = qf[0] + qf[1] + qf[2] + qf[3] + qf[4] + qf[5] + qf[6] + qf[7];
      qs += __shfl_xor(qs, 1); qs += __shfl_xor(qs, 2);
      qs += __shfl_xor(qs, 4); qs += __shfl_xor(qs, 8);
      float scl[8], pv[8];
#pragma unroll
      for (int r = 0; r < 8; ++r) {
        uint2 mv = Mreg[mi][r];
        float pp = qf[0] * ub0(mv.x) + qf[1] * ub1(mv.x) + qf[2] * ub2(mv.x) + qf[3] * ub3(mv.x)
                 + qf[4] * ub0(mv.y) + qf[5] * ub1(mv.y) + qf[6] * ub2(mv.y) + qf[7] * ub3(mv.y);
        pp += __shfl_xor(pp, 1); pp += __shfl_xor(pp, 2);
        pp += __shfl_xor(pp, 4); pp += __shfl_xor(pp, 8);
        scl[r] = sclL[mi][w * 32 + grp * 8 + r];
        pv[r] = scl[r] * (pp - 128.f * qs);
      }
      float mx = pv[0];
#pragma unroll
      for (int r = 1; r < 8; ++r) mx = fmaxf(mx, pv[r]);
      mx = fmaxf(mx, __shfl_xor(mx, 16));
      mx = fmaxf(mx, __shfl_xor(mx, 32));
      float den = 0.f, gs = 0.f;
      float acc[8] = {0.f, 0.f, 0.f, 0.f, 0.f, 0.f, 0.f, 0.f};
#pragma unroll
      for (int r = 0; r < 8; ++r) {
        float wgt = __expf(pv[r] - mx);
        den += wgt;
        float g = wgt * scl[r];
        gs += g;
        uint2 mv = Mreg[mi][r];
        acc[0] += g * ub0(mv.x); acc[1] += g * ub1(mv.x);
        acc[2] += g * ub2(mv.x); acc[3] += g * ub3(mv.x);
        acc[4] += g * ub0(mv.y); acc[5] += g * ub1(mv.y);
        acc[6] += g * ub2(mv.y); acc[7] += g * ub3(mv.y);
      }
#pragma unroll
      for (int j = 0; j < 8; ++j) {
        acc[j] += __shfl_xor(acc[j], 16);
        acc[j] += __shfl_xor(acc[j], 32);
      }
      den += __shfl_xor(den, 16); den += __shfl_xor(den, 32);
      gs += __shfl_xor(gs, 16);  gs += __shfl_xor(gs, 32);
      if (grp == 0) {
        float* dst = &macc[mi][w][colt * 8];
#pragma unroll
        for (int j = 0; j < 8; ++j) dst[j] = acc[j];
        if (colt == 0) { mmd[mi][w][0] = mx; mmd[mi][w][1] = den; mmd[mi][w][2] = gs; }
      }
    }
    __syncthreads();

    // phase C-merge: combine 8 wave-partials per m -> sb (bf16)
    if (threadIdx.x < 384) {
      int mi = threadIdx.x >> 6;
      int c0 = (threadIdx.x & 63) * 2;
      float MX = -3.0e38f;
#pragma unroll
      for (int wv = 0; wv < 8; ++wv) MX = fmaxf(MX, mmd[mi][wv][0]);
      float DEN = 0.f, GS = 0.f, s0 = 0.f, s1 = 0.f;
#pragma unroll
      for (int wv = 0; wv < 8; ++wv) {
        float fac = __expf(mmd[mi][wv][0] - MX);
        DEN += fac * mmd[mi][wv][1];
        GS += fac * mmd[mi][wv][2];
        s0 += fac * macc[mi][wv][c0];
        s1 += fac * macc[mi][wv][c0 + 1];
      }
      float rden = 1.f / DEN;
      float corr = 128.f * GS;
      *(u32*)&sb[mi][c0] = ((u32)f2bf((s1 - corr) * rden) << 16) | f2bf((s0 - corr) * rden);
    }
    __syncthreads();

    // phase D: ctx = s @ v_w^T (8 waves, ct = w)
    {
      int ct = w;
      f32x4 acc = {0.f, 0.f, 0.f, 0.f};
#pragma unroll
      for (int kq = 0; kq < 4; ++kq) {
        s8v a = *(const s8v*)(const void*)&sb[colt][kq * 32 + grp * 8];
        acc = MFMA(a, vwF[(ct * 4 + kq) * 64 + lane], acc);
      }
#pragma unroll
      for (int r = 0; r < 4; ++r) {
        int i = grp * 4 + r;
        if (i < 6) cxb[i][ct * 16 + colt] = f2bf(acc[r]);
      }
    }
    __syncthreads();

    // phase E: cell gates (48 tile-jobs over 8 waves)
#pragma unroll 1
    for (int jj = 0; jj < 6; ++jj) {
      int job = w * 6 + jj;
      int gsel = (job >= 24) ? 1 : 0;
      int ct = job - gsel * 24;
      const u16(*asrc)[136] = gsel ? hb : cxb;
      const s8v* wf = gsel ? whF : wiF;
      f32x4 acc = {0.f, 0.f, 0.f, 0.f};
#pragma unroll
      for (int kq = 0; kq < 4; ++kq) {
        s8v a = *(const s8v*)(const void*)&asrc[colt][kq * 32 + grp * 8];
        acc = MFMA(a, wf[(ct * 4 + kq) * 64 + lane], acc);
      }
      float* dst = gsel ? &gh_l[0][0] : &gi_l[0][0];
#pragma unroll
      for (int r = 0; r < 4; ++r) {
        int i = grp * 4 + r;
        if (i < 6) dst[i * 392 + ct * 16 + colt] = acc[r];
      }
    }
    __syncthreads();

    // phase F: GRU update + y_t + outputs (wave w<6 handles m=w)
    if (w < 6) {
      int mi = w, m = m0 + mi;
      float yp0 = ypl[mi][0], yp1 = ypl[mi][1], yp2 = ypl[mi][2], yp3 = ypl[mi][3];
      float hn2[2];
#pragma unroll
      for (int q = 0; q < 2; ++q) {
        int d = lane + q * 64;
        float gir = gi_l[mi][d] + cbl_i[d];
        float giz = gi_l[mi][d + 128] + cbl_i[d + 128];
        float gin = gi_l[mi][d + 256] + cbl_i[d + 256];
        const float* wy0 = &cWyl[d][0];
        const float* wy1 = &cWyl[d + 128][0];
        const float* wy2 = &cWyl[d + 256][0];
        gir += yp0 * wy0[0] + yp1 * wy0[1] + yp2 * wy0[2] + yp3 * wy0[3];
        giz += yp0 * wy1[0] + yp1 * wy1[1] + yp2 * wy1[2] + yp3 * wy1[3];
        gin += yp0 * wy2[0] + yp1 * wy2[1] + yp2 * wy2[2] + yp3 * wy2[3];
        float ghr = gh_l[mi][d] + cbl_h[d];
        float ghz = gh_l[mi][d + 128] + cbl_h[d + 128];
        float ghn = gh_l[mi][d + 256] + cbl_h[d + 256];
        float rg = sigm(gir + ghr);
        float zz = sigm(giz + ghz);
        float nn = tanh_f(gin + rg * ghn);
        float hv = (1.f - zz) * nn + zz * hfl[mi][d];
        hfl[mi][d] = hv;
        hb[mi][d] = f2bf(hv);
        hn2[q] = hv;
      }
      float p0 = hn2[0] * rwl[0][lane] + hn2[1] * rwl[0][(lane + 64) & 127];
      float p1 = hn2[0] * rwl[1][lane] + hn2[1] * rwl[1][(lane + 64) & 127];
      float p2 = hn2[0] * rwl[2][lane] + hn2[1] * rwl[2][(lane + 64) & 127];
      float p3 = hn2[0] * rwl[3][lane] + hn2[1] * rwl[3][(lane + 64) & 127];
#pragma unroll
      for (int mm = 1; mm < 64; mm <<= 1) {
        p0 += __shfl_xor(p0, mm); p1 += __shfl_xor(p1, mm);
        p2 += __shfl_xor(p2, mm); p3 += __shfl_xor(p3, mm);
      }
      if (lane < 4) {
        int c = lane;
        float pvv = (c == 0) ? p0 : (c == 1) ? p1 : (c == 2) ? p2 : p3;
        float ypc = (c == 0) ? yp0 : (c == 1) ? yp1 : (c == 2) ? yp2 : yp3;
        float yv = pvv + rbl[c] + ypc;
        __hip_atomic_store((float*)(yout + (size_t)m * 4 + c), yv,
                           __ATOMIC_RELAXED, __HIP_MEMORY_SCOPE_AGENT);
        float Yh = xlast[mi][c] + yv;
        out[((size_t)m * 4 + c) * 64 + k] = Yh;
        if (k == 0) out[393216 + (size_t)m * 4 + c] = Yh;
      }
    }

    if (k < 63) group_barrier(cnt, gen);
  }
}

// =====================================================================
extern "C" void kernel_launch(void* const* d_in, const int* in_sizes, int n_in,
                              void* d_out, int out_size, void* d_ws, size_t ws_size,
                              hipStream_t stream) {
  const float* X      = (const float*)d_in[0];
  const int*   phases = (const int*)d_in[1];
  const float* Wih    = (const float*)d_in[2];
  const float* Whh    = (const float*)d_in[3];
  const float* bih    = (const float*)d_in[4];
  const float* bhh    = (const float*)d_in[5];
  const float* lng    = (const float*)d_in[6];
  const float* lnb    = (const float*)d_in[7];
  const float* tpw    = (const float*)d_in[8];
  const float* tpb    = (const float*)d_in[9];
  const float* S      = (const float*)d_in[10];
  const float* G      = (const float*)d_in[11];
  const float* Wself  = (const float*)d_in[12];
  const float* Wneigh = (const float*)d_in[13];
  const float* snu    = (const float*)d_in[14];
  const float* kw     = (const float*)d_in[15];
  const float* vw     = (const float*)d_in[16];
  const float* cWih   = (const float*)d_in[17];
  const float* cWhh   = (const float*)d_in[18];
  const float* cbih   = (const float*)d_in[19];
  const float* cbhh   = (const float*)d_in[20];
  const float* rw     = (const float*)d_in[21];
  const float* rb     = (const float*)d_in[22];
  const float* ltau   = (const float*)d_in[23];

  char* ws = (char*)d_ws;
  u16*   Henc = (u16*)(ws + OFF_HENC);
  u16*   Mb   = (u16*)(ws + OFF_M);
  u8*    Mi8  = (u8*)(ws + OFF_MI8);
  float* Mscl = (float*)(ws + OFF_MSCL);
  float* Apf  = (float*)(ws + OFF_APF);
  u16*   Apb  = (u16*)(ws + OFF_APB);
  u16*   WnF  = (u16*)(ws + OFF_WNF);
  u16*   WsF  = (u16*)(ws + OFF_WSF);
  u16*   kwF  = (u16*)(ws + OFF_KWF);
  u16*   vwF  = (u16*)(ws + OFF_VWF);
  u16*   wiF  = (u16*)(ws + OFF_WIHF);
  u16*   whF  = (u16*)(ws + OFF_WHHF);
  float* cWy  = (float*)(ws + OFF_CWY);
  u16*   upad = (u16*)(ws + OFF_UPAD);
  float* scal = (float*)(ws + OFF_SCAL);
  float* hh   = (float*)(ws + OFF_HH);
  float* ybuf = (float*)(ws + OFF_Y);
  int*   bar  = (int*)(ws + OFF_BAR);

  hipMemsetAsync(ws + OFF_Y, 0, 49152 + 128, stream);
  hipLaunchKernelGGL(k0a, dim3(6), dim3(256), 0, stream,
                     S, G, Wneigh, snu, ltau, tpw, tpb, cWih, Apf, Apb, scal, upad, cWy);
  hipLaunchKernelGGL(k0b, dim3(672), dim3(256), 0, stream,
                     Wneigh, Wself, kw, vw, cWih, cWhh, scal, WnF, WsF, kwF, vwF, wiF, whF);
  hipLaunchKernelGGL(k1_encode, dim3(96), dim3(512), 0, stream,
                     X, Wih, Whh, bih, bhh, Henc);
  hipLaunchKernelGGL(k3_mix, dim3(4096), dim3(256), 0, stream,
                     Henc, upad, Apb, phases, lng, lnb,
                     (const s8v*)WnF, (const s8v*)WsF, Mb, hh);
  hipLaunchKernelGGL(k3b, dim3(1536), dim3(256), 0, stream, Mb, Mi8, Mscl);
  hipLaunchKernelGGL(k4p, dim3(256), dim3(512), 0, stream,
                     Mi8, Mscl, hh, ybuf, bar, Apf, phases, scal,
                     (const s8v*)kwF, (const s8v*)vwF, (const s8v*)wiF, (const s8v*)whF,
                     cWy, cbih, cbhh, rw, rb, X, (float*)d_out);
}

// Round 11
// 2077.047 us; speedup vs baseline: 2.0719x; 2.0719x over previous
//
#include <hip/hip_runtime.h>
#include <stdint.h>

typedef unsigned int u32;
typedef unsigned short u16;
typedef unsigned char u8;
typedef __attribute__((ext_vector_type(8))) short s8v;
typedef __attribute__((ext_vector_type(8))) __bf16 bf16x8;
typedef __attribute__((ext_vector_type(4))) float f32x4;

// ---------------- workspace layout (bytes) ----------------
#define OFF_HENC 0ull                 // [16][96][256][128] bf16 (raw h, pre-LN)
#define OFF_M    100663296ull         // [16][96][256][128] bf16 (intermediate)
#define OFF_MI8  201326592ull         // [1536][256][128] u8   (50331648)
#define OFF_MSCL 251658240ull         // [1536][256] f32       (1572864)
#define OFF_APF  253231104ull         // [4][96][96] f32
#define OFF_APB  253378560ull         // [4][96][96] bf16
#define OFF_WNF  253452288ull         // [8*5][64][8] bf16
#define OFF_WSF  253493248ull         // [8*5][64][8] bf16
#define OFF_KWF  253534208ull         // [8*4][64][8] bf16
#define OFF_VWF  253566976ull         // [8*4][64][8] bf16
#define OFF_WIHF 253599744ull         // [24*4][64][8] bf16
#define OFF_WHHF 253698048ull         // [24*4][64][8] bf16
#define OFF_CWY  253796352ull         // [384][4] f32
#define OFF_UPAD 253802496ull         // [256][32] bf16
#define OFF_SCAL 253818880ull         // scal[0]=1/sigma, scal[1]=exp(log_tau)
#define OFF_HH   253819136ull         // [1536][128] f32 head hidden state
#define OFF_Y    254605568ull         // 2 x [1536][4] f32 ping-pong y

__device__ __forceinline__ u16 f2bf(float f) {
  u32 u = __float_as_uint(f);
  u32 r = u + 0x7fffu + ((u >> 16) & 1u);
  return (u16)(r >> 16);
}
__device__ __forceinline__ float bf2f(u16 h) { return __uint_as_float(((u32)h) << 16); }
__device__ __forceinline__ float blo(u32 u) { return __uint_as_float(u << 16); }
__device__ __forceinline__ float bhi(u32 u) { return __uint_as_float(u & 0xffff0000u); }
__device__ __forceinline__ float sigm(float x) { return 1.f / (1.f + __expf(-x)); }
__device__ __forceinline__ float tanh_f(float x) {
  float a = fminf(fabsf(x), 15.f);
  float e = __expf(2.f * a);
  float t = (e - 1.f) / (e + 1.f);
  return copysignf(t, x);
}
__device__ __forceinline__ f32x4 MFMA(s8v a, s8v b, f32x4 c) {
  return __builtin_amdgcn_mfma_f32_16x16x32_bf16(
      __builtin_bit_cast(bf16x8, a), __builtin_bit_cast(bf16x8, b), c, 0, 0, 0);
}
__device__ __forceinline__ float ub0(u32 x) { return (float)(x & 0xffu); }
__device__ __forceinline__ float ub1(u32 x) { return (float)((x >> 8) & 0xffu); }
__device__ __forceinline__ float ub2(u32 x) { return (float)((x >> 16) & 0xffu); }
__device__ __forceinline__ float ub3(u32 x) { return (float)((x >> 24) & 0xffu); }

// =====================================================================
// K0a: phase-adjacency (per p), spectral norm sigma, tpos table, cWy
// =====================================================================
__global__ void k0a(const float* __restrict__ S, const float* __restrict__ G,
                    const float* __restrict__ Wn, const float* __restrict__ snu,
                    const float* __restrict__ logtau, const float* __restrict__ tpw,
                    const float* __restrict__ tpb, const float* __restrict__ cWih,
                    float* __restrict__ Apf, u16* __restrict__ Apb,
                    float* __restrict__ scal, u16* __restrict__ upad,
                    float* __restrict__ cWy) {
  int tid = threadIdx.x;
  int blk = blockIdx.x;
  if (blk < 4) {
    int p = blk;
    __shared__ float gg[96];
    __shared__ float gfac;
    if (tid < 96) {
      float x = G[p * 96 + tid];
      float sp = fmaxf(x, 0.f) + log1pf(__expf(-fabsf(x)));
      gg[tid] = sp + 1e-6f;
    }
    __syncthreads();
    if (tid == 0) {
      float s = 0;
      for (int i = 0; i < 96; ++i) s += gg[i];
      gfac = 96.f / fmaxf(s, 1e-6f);
    }
    __syncthreads();
    if (tid < 96) {
      int i = tid;
      const float* srow = S + ((size_t)p * 96 + i) * 96;
      float den = 0;
      for (int j = 0; j < 96; ++j) { float v = (j == i) ? 0.f : srow[j]; den += fabsf(v); }
      den = fmaxf(den, 1e-6f);
      float sc = gg[i] * gfac / den;
      for (int j = 0; j < 96; ++j) {
        float v = (j == i) ? 0.f : srow[j];
        float a = v * sc;
        Apf[((size_t)p * 96 + i) * 96 + j] = a;
        Apb[((size_t)p * 96 + i) * 96 + j] = f2bf(a);
      }
    }
  } else if (blk == 4) {
    __shared__ float sv[144];
    __shared__ float su[128];
    __shared__ float snorm;
    if (tid < 144) {
      float a = 0;
      for (int d = 0; d < 128; ++d) a += Wn[d * 144 + tid] * snu[d];
      sv[tid] = a;
    }
    __syncthreads();
    if (tid == 0) {
      float s = 0;
      for (int j = 0; j < 144; ++j) s += sv[j] * sv[j];
      snorm = sqrtf(s) + 1e-12f;
    }
    __syncthreads();
    if (tid < 144) sv[tid] = sv[tid] / snorm;
    __syncthreads();
    if (tid < 128) {
      float a = 0;
      for (int j = 0; j < 144; ++j) a += Wn[tid * 144 + j] * sv[j];
      su[tid] = a;
    }
    __syncthreads();
    if (tid == 0) {
      float ss = 0;
      for (int d = 0; d < 128; ++d) ss += su[d] * su[d];
      float nu = sqrtf(ss);
      float sigma = ss / (nu + 1e-12f);
      scal[0] = 1.f / sigma;
      scal[1] = __expf(logtau[0]);
    }
  } else {
    for (int idx = tid; idx < 256 * 32; idx += 256) {
      int t = idx >> 5, kk = idx & 31;
      float v = 0.f;
      if (kk < 16) v = tanh_f((float)t * (1.f / 255.f) * tpw[kk] + tpb[kk]);
      upad[idx] = f2bf(v);
    }
    for (int idx = tid; idx < 1536; idx += 256)
      cWy[idx] = cWih[(idx >> 2) * 132 + 128 + (idx & 3)];
  }
}

// =====================================================================
// K0b: pack all B-operand fragment arrays
// =====================================================================
__global__ void k0b(const float* __restrict__ Wn, const float* __restrict__ Ws,
                    const float* __restrict__ kw, const float* __restrict__ vw,
                    const float* __restrict__ cWih, const float* __restrict__ cWhh,
                    const float* __restrict__ scal,
                    u16* __restrict__ WnF, u16* __restrict__ WsF,
                    u16* __restrict__ kwF, u16* __restrict__ vwF,
                    u16* __restrict__ wiF, u16* __restrict__ whF) {
  int idx = blockIdx.x * 256 + threadIdx.x;
  int lane, j, ctkq, ct, kq, col, k;
  if (idx < 20480) {
    ctkq = idx >> 9; lane = (idx >> 3) & 63; j = idx & 7;
    ct = ctkq / 5; kq = ctkq % 5;
    col = ct * 16 + (lane & 15); k = kq * 32 + ((lane >> 4) << 3) + j;
    float v = (k < 144) ? Wn[col * 144 + k] * scal[0] : 0.f;
    WnF[idx] = f2bf(v);
    return;
  }
  idx -= 20480;
  if (idx < 20480) {
    ctkq = idx >> 9; lane = (idx >> 3) & 63; j = idx & 7;
    ct = ctkq / 5; kq = ctkq % 5;
    col = ct * 16 + (lane & 15); k = kq * 32 + ((lane >> 4) << 3) + j;
    float v = (k < 144) ? Ws[col * 144 + k] : 0.f;
    WsF[idx] = f2bf(v);
    return;
  }
  idx -= 20480;
  if (idx < 16384) {
    ctkq = idx >> 9; lane = (idx >> 3) & 63; j = idx & 7;
    ct = ctkq >> 2; kq = ctkq & 3;
    col = ct * 16 + (lane & 15); k = kq * 32 + ((lane >> 4) << 3) + j;
    kwF[idx] = f2bf(kw[k * 128 + col]);
    return;
  }
  idx -= 16384;
  if (idx < 16384) {
    ctkq = idx >> 9; lane = (idx >> 3) & 63; j = idx & 7;
    ct = ctkq >> 2; kq = ctkq & 3;
    col = ct * 16 + (lane & 15); k = kq * 32 + ((lane >> 4) << 3) + j;
    vwF[idx] = f2bf(vw[col * 128 + k]);
    return;
  }
  idx -= 16384;
  if (idx < 49152) {
    ctkq = idx >> 9; lane = (idx >> 3) & 63; j = idx & 7;
    ct = ctkq >> 2; kq = ctkq & 3;
    col = ct * 16 + (lane & 15); k = kq * 32 + ((lane >> 4) << 3) + j;
    wiF[idx] = f2bf(cWih[col * 132 + k]);
    return;
  }
  idx -= 49152;
  if (idx < 49152) {
    ctkq = idx >> 9; lane = (idx >> 3) & 63; j = idx & 7;
    ct = ctkq >> 2; kq = ctkq & 3;
    col = ct * 16 + (lane & 15); k = kq * 32 + ((lane >> 4) << 3) + j;
    whF[idx] = f2bf(cWhh[col * 128 + k]);
  }
}

// =====================================================================
// K1: GRU encode, LN deferred to k3. One block per n, 8 waves.
// =====================================================================
__launch_bounds__(512)
__global__ void k1_encode(const float* __restrict__ X, const float* __restrict__ Wih,
                          const float* __restrict__ Whh, const float* __restrict__ bih,
                          const float* __restrict__ bhh, u16* __restrict__ Henc) {
  const int n = blockIdx.x;
  const int lane = threadIdx.x & 63, w = threadIdx.x >> 6;
  const int colt = lane & 15, grp = lane >> 4;
  __shared__ __align__(16) float Xl[16][256][4];
  __shared__ __align__(16) u16 hb[2][16][136];

  for (int idx = threadIdx.x; idx < 16 * 1024; idx += 512) {
    int b = idx >> 10, rem = idx & 1023, c = rem >> 8, t = rem & 255;
    Xl[b][t][c] = X[(((size_t)b * 96 + n) * 4 + c) * 256 + t];
  }
  for (int idx = threadIdx.x; idx < 2 * 16 * 136; idx += 512) (&hb[0][0][0])[idx] = 0;

  s8v bfr[3][4];
#pragma unroll
  for (int g = 0; g < 3; ++g) {
    int col = g * 128 + w * 16 + colt;
    const float* wr = Whh + ((size_t)n * 384 + col) * 128;
#pragma unroll
    for (int kq = 0; kq < 4; ++kq) {
      int k0 = kq * 32 + grp * 8;
      float4 f0 = *(const float4*)(wr + k0);
      float4 f1 = *(const float4*)(wr + k0 + 4);
      union { s8v v; u16 s[8]; } tmp;
      tmp.s[0] = f2bf(f0.x); tmp.s[1] = f2bf(f0.y); tmp.s[2] = f2bf(f0.z); tmp.s[3] = f2bf(f0.w);
      tmp.s[4] = f2bf(f1.x); tmp.s[5] = f2bf(f1.y); tmp.s[6] = f2bf(f1.z); tmp.s[7] = f2bf(f1.w);
      bfr[g][kq] = tmp.v;
    }
  }
  float wihr[3][4], bi[3], bh[3];
#pragma unroll
  for (int g = 0; g < 3; ++g) {
    int col = g * 128 + w * 16 + colt;
    float4 wv = *(const float4*)(Wih + ((size_t)n * 384 + col) * 4);
    wihr[g][0] = wv.x; wihr[g][1] = wv.y; wihr[g][2] = wv.z; wihr[g][3] = wv.w;
    bi[g] = bih[n * 384 + col];
    bh[g] = bhh[n * 384 + col];
  }
  float h_reg[4] = {0.f, 0.f, 0.f, 0.f};
  __syncthreads();

  int cur = 0;
  for (int t = 0; t < 256; ++t) {
    s8v a[4];
#pragma unroll
    for (int kq = 0; kq < 4; ++kq)
      a[kq] = *(const s8v*)(const void*)&hb[cur][colt][kq * 32 + grp * 8];
    f32x4 acc0 = {0.f, 0.f, 0.f, 0.f}, acc1 = acc0, acc2 = acc0;
#pragma unroll
    for (int kq = 0; kq < 4; ++kq) {
      acc0 = MFMA(a[kq], bfr[0][kq], acc0);
      acc1 = MFMA(a[kq], bfr[1][kq], acc1);
      acc2 = MFMA(a[kq], bfr[2][kq], acc2);
    }
#pragma unroll
    for (int r = 0; r < 4; ++r) {
      int b = grp * 4 + r;
      float4 x4 = *(const float4*)&Xl[b][t][0];
      float gir = bi[0] + x4.x * wihr[0][0] + x4.y * wihr[0][1] + x4.z * wihr[0][2] + x4.w * wihr[0][3];
      float giz = bi[1] + x4.x * wihr[1][0] + x4.y * wihr[1][1] + x4.z * wihr[1][2] + x4.w * wihr[1][3];
      float gin = bi[2] + x4.x * wihr[2][0] + x4.y * wihr[2][1] + x4.z * wihr[2][2] + x4.w * wihr[2][3];
      float rr = sigm(gir + acc0[r] + bh[0]);
      float zz = sigm(giz + acc1[r] + bh[1]);
      float nn = tanh_f(gin + rr * (acc2[r] + bh[2]));
      float hv = (1.f - zz) * nn + zz * h_reg[r];
      h_reg[r] = hv;
      u16 hvb = f2bf(hv);
      Henc[(((size_t)b * 96 + n) * 256 + t) * 128 + w * 16 + colt] = hvb;
      hb[cur ^ 1][b][w * 16 + colt] = hvb;
    }
    __syncthreads();
    cur ^= 1;
  }
}

// =====================================================================
// K3: per (b,t): LN -> Hc, Hn = Wsn@Hc, Zn = A@Hn, Hs = Wself@Hc,
// Z = leaky(Hs+Zn) -> M (bf16); at t=255 also h0 -> hh.
// =====================================================================
__launch_bounds__(256, 2)
__global__ void k3_mix(const u16* __restrict__ Henc, const u16* __restrict__ upad,
                       const u16* __restrict__ Apb, const int* __restrict__ phases,
                       const float* __restrict__ lng, const float* __restrict__ lnb,
                       const s8v* __restrict__ WnF, const s8v* __restrict__ WsF,
                       u16* __restrict__ M, float* __restrict__ hh) {
  const int b = blockIdx.x >> 8, t = blockIdx.x & 255;
  const int p = phases[b];
  const int lane = threadIdx.x & 63, w = threadIdx.x >> 6;
  const int colt = lane & 15, grp = lane >> 4;
  __shared__ __align__(16) u16 Hc[96][168];
  __shared__ __align__(16) u16 HnT[128][104];
  __shared__ float lnG[128], lnB[128];

  const u16* src = Henc + ((size_t)b * 96 * 256 + t) * 128;
  for (int u = threadIdx.x; u < 96 * 16; u += 256) {
    int j = u >> 4, ch = u & 15;
    *(uint4*)&Hc[j][ch * 8] = *(const uint4*)(src + (size_t)j * 256 * 128 + ch * 8);
  }
  for (int u = threadIdx.x; u < 96 * 16; u += 256) {
    int j = u >> 4, ch = u & 15;
    *(u32*)&Hc[j][128 + ch * 2] = *(const u32*)(upad + t * 32 + ch * 2);
  }
  if (threadIdx.x < 128) {
    lnG[threadIdx.x] = lng[threadIdx.x];
    lnB[threadIdx.x] = lnb[threadIdx.x];
  }
  __syncthreads();
  if (threadIdx.x < 96) {
    int j = threadIdx.x;
    float s = 0.f, q = 0.f;
#pragma unroll 4
    for (int d = 0; d < 128; ++d) {
      float v = bf2f(Hc[j][d]);
      s += v; q += v * v;
    }
    float mu = s * (1.f / 128.f);
    float var = q * (1.f / 128.f) - mu * mu;
    float rs = rsqrtf(var + 1e-5f);
#pragma unroll 4
    for (int d = 0; d < 128; ++d) {
      float v = bf2f(Hc[j][d]);
      Hc[j][d] = f2bf((v - mu) * rs * lnG[d] + lnB[d]);
    }
  }
  __syncthreads();
  for (int jj = 0; jj < 12; ++jj) {
    int job = w * 12 + jj;
    int jt = job >> 3, ct = job & 7;
    f32x4 acc = {0.f, 0.f, 0.f, 0.f};
#pragma unroll
    for (int kq = 0; kq < 5; ++kq) {
      s8v a = *(const s8v*)(const void*)&Hc[jt * 16 + colt][kq * 32 + grp * 8];
      acc = MFMA(a, WnF[(ct * 5 + kq) * 64 + lane], acc);
    }
    int d = ct * 16 + colt, j0 = jt * 16 + grp * 4;
    u32 w0 = ((u32)f2bf(acc[1]) << 16) | f2bf(acc[0]);
    u32 w1 = ((u32)f2bf(acc[3]) << 16) | f2bf(acc[2]);
    *(u32*)&HnT[d][j0] = w0;
    *(u32*)&HnT[d][j0 + 2] = w1;
  }
  __syncthreads();
  for (int jj = 0; jj < 12; ++jj) {
    int job = w * 12 + jj;
    int it = job >> 3, ct = job & 7;
    f32x4 accZ = {0.f, 0.f, 0.f, 0.f}, accS = accZ;
#pragma unroll
    for (int kq = 0; kq < 3; ++kq) {
      s8v a = *(const s8v*)(const void*)(Apb + ((size_t)p * 96 + it * 16 + colt) * 96 + kq * 32 + grp * 8);
      s8v bb = *(const s8v*)(const void*)&HnT[ct * 16 + colt][kq * 32 + grp * 8];
      accZ = MFMA(a, bb, accZ);
    }
#pragma unroll
    for (int kq = 0; kq < 5; ++kq) {
      s8v a = *(const s8v*)(const void*)&Hc[it * 16 + colt][kq * 32 + grp * 8];
      accS = MFMA(a, WsF[(ct * 5 + kq) * 64 + lane], accS);
    }
    int d = ct * 16 + colt;
#pragma unroll
    for (int r = 0; r < 4; ++r) {
      int i = it * 16 + grp * 4 + r;
      float z = accS[r] + accZ[r];
      z = z >= 0.f ? z : 0.1f * z;
      M[(((size_t)b * 96 + i) * 256 + t) * 128 + d] = f2bf(z);
      if (t == 255) hh[((size_t)b * 96 + i) * 128 + d] = z;
    }
  }
}

// =====================================================================
// K3b: quantize M bf16 -> int8 row-scaled. Block = m (1536), thread = t.
// u = rint(z*127/rowmax)+128; scale = rowmax/127.
// =====================================================================
__launch_bounds__(256)
__global__ void k3b(const u16* __restrict__ Mbf, u8* __restrict__ Mi8,
                    float* __restrict__ Mscl) {
  const size_t m = blockIdx.x;
  const int t = threadIdx.x;
  const u16* src = Mbf + (m * 256 + t) * 128;
  float vals[128];
  float mx = 0.f;
#pragma unroll 8
  for (int d = 0; d < 128; ++d) {
    float f = bf2f(src[d]);
    vals[d] = f;
    mx = fmaxf(mx, fabsf(f));
  }
  float scale = mx * (1.f / 127.f);
  float inv = (mx > 0.f) ? (127.f / mx) : 0.f;
  u32* dst = (u32*)(Mi8 + (m * 256 + t) * 128);
#pragma unroll 8
  for (int dw = 0; dw < 32; ++dw) {
    u32 packed = 0;
#pragma unroll
    for (int j = 0; j < 4; ++j) {
      int q = (int)rintf(vals[dw * 4 + j] * inv) + 128;
      packed |= ((u32)(q & 0xff)) << (8 * j);
    }
    dst[dw] = packed;
  }
  Mscl[m * 256 + t] = scale;
}

// =====================================================================
// K4: one head step (64 launches). 256 blocks x 8 waves; block owns 6 m.
// Phase C: batch-load 16 int8 row-tiles (uint2) + row scales, two-pass
// softmax + weighted sum with the exact bias-correction trick.
// =====================================================================
__launch_bounds__(512)
__global__ void k4_step(int k, const u8* __restrict__ Mi8, const float* __restrict__ Mscl,
                        float* __restrict__ hh,
                        const float* __restrict__ yin, float* __restrict__ yout,
                        const float* __restrict__ Apf, const int* __restrict__ phases,
                        const float* __restrict__ scal,
                        const s8v* __restrict__ kwF, const s8v* __restrict__ vwF,
                        const s8v* __restrict__ wiF, const s8v* __restrict__ whF,
                        const float* __restrict__ cWy, const float* __restrict__ cbih,
                        const float* __restrict__ cbhh, const float* __restrict__ rw,
                        const float* __restrict__ rb, const float* __restrict__ X,
                        float* __restrict__ out) {
  const int bl = blockIdx.x;
  const int b = bl >> 4, n0 = (bl & 15) * 6, m0 = b * 96 + n0;
  const int lane = threadIdx.x & 63, w = threadIdx.x >> 6;
  const int colt = lane & 15, grp = lane >> 4;
  __shared__ float hfl[6][128];
  __shared__ __align__(16) u16 hb[16][136];
  __shared__ __align__(16) u16 qb[6][128];
  __shared__ __align__(16) u16 sb[16][136];
  __shared__ __align__(16) u16 cxb[16][136];
  __shared__ __align__(16) float macc[6][16][128];
  __shared__ float mmd[6][16][4];
  __shared__ float sclL[6][256];
  __shared__ float gi_l[6][392];
  __shared__ float gh_l[6][392];
  __shared__ float ypl[6][4];
  const float scale = scal[1];

  // phase A: load h (rows 0..5), zero pad rows; stage row scales; y-prop
  for (int idx = threadIdx.x; idx < 2048; idx += 512) {
    int i = idx >> 7, d = idx & 127;
    float hv = 0.f;
    if (i < 6) {
      hv = hh[(size_t)(m0 + i) * 128 + d];
      hfl[i][d] = hv;
    } else {
      sb[i][d] = 0;
      cxb[i][d] = 0;
    }
    hb[i][d] = f2bf(hv);
  }
  for (int idx = threadIdx.x; idx < 1536; idx += 512) {
    int mi = idx >> 8, t = idx & 255;
    sclL[mi][t] = Mscl[(size_t)(m0 + mi) * 256 + t];
  }
  if (w < 6) {
    int i = w, ni = n0 + w;
    const float* arow = Apf + ((size_t)phases[b] * 96 + ni) * 96;
    float acc[4] = {0.f, 0.f, 0.f, 0.f};
    for (int j = lane; j < 96; j += 64) {
      float av = arow[j];
      const float* yr = yin + ((size_t)b * 96 + j) * 4;
      acc[0] += av * yr[0]; acc[1] += av * yr[1];
      acc[2] += av * yr[2]; acc[3] += av * yr[3];
    }
#pragma unroll
    for (int mm = 1; mm < 64; mm <<= 1) {
#pragma unroll
      for (int c = 0; c < 4; ++c) acc[c] += __shfl_xor(acc[c], mm);
    }
    if (lane < 4) ypl[i][lane] = yin[((size_t)b * 96 + ni) * 4 + lane] + 0.3f * acc[lane];
  }
  __syncthreads();

  // phase B: q = h @ k_w (scale folded in)
  {
    int ct = w;
    f32x4 acc = {0.f, 0.f, 0.f, 0.f};
#pragma unroll
    for (int kq = 0; kq < 4; ++kq) {
      s8v a = *(const s8v*)(const void*)&hb[colt][kq * 32 + grp * 8];
      acc = MFMA(a, kwF[(ct * 4 + kq) * 64 + lane], acc);
    }
#pragma unroll
    for (int r = 0; r < 4; ++r) {
      int i = grp * 4 + r;
      if (i < 6) qb[i][ct * 16 + colt] = f2bf(acc[r] * scale);
    }
  }
  __syncthreads();

  // phase C: int8 scores+softmax+weighted-sum, single pass over Mi8.
  // 24 units = (m in 0..5) x (quarter q in 0..3); unit u -> wave u%8.
  // Lane (grp,colt): rows t=qq*64+it*4+grp (it=0..15), byte-cols colt*8..+7.
#pragma unroll 1
  for (int uu = 0; uu < 3; ++uu) {
    int u = w + uu * 8;
    int mi = u >> 2, qq = u & 3;
    float qf[8];
    const u32* qsrc = (const u32*)&qb[mi][colt * 8];
#pragma unroll
    for (int x = 0; x < 4; ++x) { u32 v = qsrc[x]; qf[2 * x] = blo(v); qf[2 * x + 1] = bhi(v); }
    float qs = qf[0] + qf[1] + qf[2] + qf[3] + qf[4] + qf[5] + qf[6] + qf[7];
    qs += __shfl_xor(qs, 1); qs += __shfl_xor(qs, 2);
    qs += __shfl_xor(qs, 4); qs += __shfl_xor(qs, 8);
    const u8* mp = Mi8 + ((size_t)(m0 + mi) * 256 + qq * 64 + grp) * 128 + colt * 8;
    uint2 mv[16];
#pragma unroll
    for (int it = 0; it < 16; ++it) mv[it] = *(const uint2*)(mp + (size_t)it * 512);
    float scl[16];
#pragma unroll
    for (int it = 0; it < 16; ++it) scl[it] = sclL[mi][qq * 64 + it * 4 + grp];
    float p[16];
#pragma unroll
    for (int it = 0; it < 16; ++it) {
      uint2 v = mv[it];
      float pp = qf[0] * ub0(v.x) + qf[1] * ub1(v.x) + qf[2] * ub2(v.x) + qf[3] * ub3(v.x)
               + qf[4] * ub0(v.y) + qf[5] * ub1(v.y) + qf[6] * ub2(v.y) + qf[7] * ub3(v.y);
      pp += __shfl_xor(pp, 1); pp += __shfl_xor(pp, 2);
      pp += __shfl_xor(pp, 4); pp += __shfl_xor(pp, 8);
      p[it] = scl[it] * (pp - 128.f * qs);
    }
    float mx = p[0];
#pragma unroll
    for (int it = 1; it < 16; ++it) mx = fmaxf(mx, p[it]);
    float den = 0.f, gs = 0.f;
    float acc[8] = {0.f, 0.f, 0.f, 0.f, 0.f, 0.f, 0.f, 0.f};
#pragma unroll
    for (int it = 0; it < 16; ++it) {
      float wgt = __expf(p[it] - mx);
      den += wgt;
      float g = wgt * scl[it];
      gs += g;
      uint2 v = mv[it];
      acc[0] += g * ub0(v.x); acc[1] += g * ub1(v.x);
      acc[2] += g * ub2(v.x); acc[3] += g * ub3(v.x);
      acc[4] += g * ub0(v.y); acc[5] += g * ub1(v.y);
      acc[6] += g * ub2(v.y); acc[7] += g * ub3(v.y);
    }
    int su = qq * 4 + grp;
    float* dst = &macc[mi][su][colt * 8];
#pragma unroll
    for (int j = 0; j < 8; ++j) dst[j] = acc[j];
    if (colt == 0) { mmd[mi][su][0] = mx; mmd[mi][su][1] = den; mmd[mi][su][2] = gs; }
  }
  __syncthreads();

  // phase C-merge: combine 16 sub-units per m -> sb (bf16)
  // s_d = (Sum fac*acc_d - 128*Sum fac*gs) / (Sum fac*den)
  if (w < 6) {
    int i = w;
    float MX = -3.0e38f;
#pragma unroll
    for (int uy = 0; uy < 16; ++uy) MX = fmaxf(MX, mmd[i][uy][0]);
    float DEN = 0.f, GS = 0.f, s0 = 0.f, s1 = 0.f;
    int c0 = lane * 2;
#pragma unroll
    for (int uy = 0; uy < 16; ++uy) {
      float fac = __expf(mmd[i][uy][0] - MX);
      DEN += fac * mmd[i][uy][1];
      GS += fac * mmd[i][uy][2];
      s0 += fac * macc[i][uy][c0];
      s1 += fac * macc[i][uy][c0 + 1];
    }
    float rden = 1.f / DEN;
    float corr = 128.f * GS;
    *(u32*)&sb[i][c0] = ((u32)f2bf((s1 - corr) * rden) << 16) | f2bf((s0 - corr) * rden);
  }
  __syncthreads();

  // phase D: ctx = s @ v_w^T
  {
    int ct = w;
    f32x4 acc = {0.f, 0.f, 0.f, 0.f};
#pragma unroll
    for (int kq = 0; kq < 4; ++kq) {
      s8v a = *(const s8v*)(const void*)&sb[colt][kq * 32 + grp * 8];
      acc = MFMA(a, vwF[(ct * 4 + kq) * 64 + lane], acc);
    }
#pragma unroll
    for (int r = 0; r < 4; ++r) {
      int i = grp * 4 + r;
      if (i < 6) cxb[i][ct * 16 + colt] = f2bf(acc[r]);
    }
  }
  __syncthreads();

  // phase E: cell gates gi (ctx part) and gh
  for (int jj = 0; jj < 6; ++jj) {
    int job = w * 6 + jj;
    int gsel = (job >= 24) ? 1 : 0;
    int ct = job - gsel * 24;
    const u16(*asrc)[136] = gsel ? hb : cxb;
    const s8v* wf = gsel ? whF : wiF;
    f32x4 acc = {0.f, 0.f, 0.f, 0.f};
#pragma unroll
    for (int kq = 0; kq < 4; ++kq) {
      s8v a = *(const s8v*)(const void*)&asrc[colt][kq * 32 + grp * 8];
      acc = MFMA(a, wf[(ct * 4 + kq) * 64 + lane], acc);
    }
    float* dst = gsel ? &gh_l[0][0] : &gi_l[0][0];
#pragma unroll
    for (int r = 0; r < 4; ++r) {
      int i = grp * 4 + r;
      if (i < 6) dst[i * 392 + ct * 16 + colt] = acc[r];
    }
  }
  __syncthreads();

  // phase F: GRU update + y_t + outputs
  if (w < 6) {
    int i = w, m = m0 + i;
    float yp0 = ypl[i][0], yp1 = ypl[i][1], yp2 = ypl[i][2], yp3 = ypl[i][3];
    float hn2[2];
#pragma unroll
    for (int q = 0; q < 2; ++q) {
      int d = lane + q * 64;
      float gir = gi_l[i][d] + cbih[d];
      float giz = gi_l[i][d + 128] + cbih[d + 128];
      float gin = gi_l[i][d + 256] + cbih[d + 256];
      const float* wy0 = cWy + (size_t)d * 4;
      const float* wy1 = cWy + (size_t)(d + 128) * 4;
      const float* wy2 = cWy + (size_t)(d + 256) * 4;
      gir += yp0 * wy0[0] + yp1 * wy0[1] + yp2 * wy0[2] + yp3 * wy0[3];
      giz += yp0 * wy1[0] + yp1 * wy1[1] + yp2 * wy1[2] + yp3 * wy1[3];
      gin += yp0 * wy2[0] + yp1 * wy2[1] + yp2 * wy2[2] + yp3 * wy2[3];
      float ghr = gh_l[i][d] + cbhh[d];
      float ghz = gh_l[i][d + 128] + cbhh[d + 128];
      float ghn = gh_l[i][d + 256] + cbhh[d + 256];
      float rr = sigm(gir + ghr);
      float zz = sigm(giz + ghz);
      float nn = tanh_f(gin + rr * ghn);
      float hv = (1.f - zz) * nn + zz * hfl[i][d];
      hh[(size_t)m * 128 + d] = hv;
      hn2[q] = hv;
    }
    float p0 = hn2[0] * rw[0 * 128 + lane] + hn2[1] * rw[0 * 128 + lane + 64];
    float p1 = hn2[0] * rw[1 * 128 + lane] + hn2[1] * rw[1 * 128 + lane + 64];
    float p2 = hn2[0] * rw[2 * 128 + lane] + hn2[1] * rw[2 * 128 + lane + 64];
    float p3 = hn2[0] * rw[3 * 128 + lane] + hn2[1] * rw[3 * 128 + lane + 64];
#pragma unroll
    for (int mm = 1; mm < 64; mm <<= 1) {
      p0 += __shfl_xor(p0, mm); p1 += __shfl_xor(p1, mm);
      p2 += __shfl_xor(p2, mm); p3 += __shfl_xor(p3, mm);
    }
    if (lane < 4) {
      int c = lane;
      float pv = (c == 0) ? p0 : (c == 1) ? p1 : (c == 2) ? p2 : p3;
      float ypc = (c == 0) ? yp0 : (c == 1) ? yp1 : (c == 2) ? yp2 : yp3;
      float yv = pv + rb[c] + ypc;
      yout[(size_t)m * 4 + c] = yv;
      float xl = X[((size_t)m * 4 + c) * 256 + 255];
      float Yh = xl + yv;
      out[((size_t)m * 4 + c) * 64 + k] = Yh;
      if (k == 0) out[393216 + (size_t)m * 4 + c] = Yh;
    }
  }
}

// =====================================================================
extern "C" void kernel_launch(void* const* d_in, const int* in_sizes, int n_in,
                              void* d_out, int out_size, void* d_ws, size_t ws_size,
                              hipStream_t stream) {
  const float* X      = (const float*)d_in[0];
  const int*   phases = (const int*)d_in[1];
  const float* Wih    = (const float*)d_in[2];
  const float* Whh    = (const float*)d_in[3];
  const float* bih    = (const float*)d_in[4];
  const float* bhh    = (const float*)d_in[5];
  const float* lng    = (const float*)d_in[6];
  const float* lnb    = (const float*)d_in[7];
  const float* tpw    = (const float*)d_in[8];
  const float* tpb    = (const float*)d_in[9];
  const float* S      = (const float*)d_in[10];
  const float* G      = (const float*)d_in[11];
  const float* Wself  = (const float*)d_in[12];
  const float* Wneigh = (const float*)d_in[13];
  const float* snu    = (const float*)d_in[14];
  const float* kw     = (const float*)d_in[15];
  const float* vw     = (const float*)d_in[16];
  const float* cWih   = (const float*)d_in[17];
  const float* cWhh   = (const float*)d_in[18];
  const float* cbih   = (const float*)d_in[19];
  const float* cbhh   = (const float*)d_in[20];
  const float* rw     = (const float*)d_in[21];
  const float* rb     = (const float*)d_in[22];
  const float* ltau   = (const float*)d_in[23];

  char* ws = (char*)d_ws;
  u16*   Henc = (u16*)(ws + OFF_HENC);
  u16*   Mb   = (u16*)(ws + OFF_M);
  u8*    Mi8  = (u8*)(ws + OFF_MI8);
  float* Mscl = (float*)(ws + OFF_MSCL);
  float* Apf  = (float*)(ws + OFF_APF);
  u16*   Apb  = (u16*)(ws + OFF_APB);
  u16*   WnF  = (u16*)(ws + OFF_WNF);
  u16*   WsF  = (u16*)(ws + OFF_WSF);
  u16*   kwF  = (u16*)(ws + OFF_KWF);
  u16*   vwF  = (u16*)(ws + OFF_VWF);
  u16*   wiF  = (u16*)(ws + OFF_WIHF);
  u16*   whF  = (u16*)(ws + OFF_WHHF);
  float* cWy  = (float*)(ws + OFF_CWY);
  u16*   upad = (u16*)(ws + OFF_UPAD);
  float* scal = (float*)(ws + OFF_SCAL);
  float* hh   = (float*)(ws + OFF_HH);

  hipMemsetAsync(ws + OFF_Y, 0, 49152, stream);
  hipLaunchKernelGGL(k0a, dim3(6), dim3(256), 0, stream,
                     S, G, Wneigh, snu, ltau, tpw, tpb, cWih, Apf, Apb, scal, upad, cWy);
  hipLaunchKernelGGL(k0b, dim3(672), dim3(256), 0, stream,
                     Wneigh, Wself, kw, vw, cWih, cWhh, scal, WnF, WsF, kwF, vwF, wiF, whF);
  hipLaunchKernelGGL(k1_encode, dim3(96), dim3(512), 0, stream,
                     X, Wih, Whh, bih, bhh, Henc);
  hipLaunchKernelGGL(k3_mix, dim3(4096), dim3(256), 0, stream,
                     Henc, upad, Apb, phases, lng, lnb,
                     (const s8v*)WnF, (const s8v*)WsF, Mb, hh);
  hipLaunchKernelGGL(k3b, dim3(1536), dim3(256), 0, stream, Mb, Mi8, Mscl);
  for (int k = 0; k < 64; ++k) {
    const float* yi = (const float*)(ws + OFF_Y + (size_t)(k & 1) * 24576);
    float*       yo = (float*)(ws + OFF_Y + (size_t)((k + 1) & 1) * 24576);
    hipLaunchKernelGGL(k4_step, dim3(256), dim3(512), 0, stream,
                       k, Mi8, Mscl, hh, yi, yo, Apf, phases, scal,
                       (const s8v*)kwF, (const s8v*)vwF, (const s8v*)wiF, (const s8v*)whF,
                       cWy, cbih, cbhh, rw, rb, X, (float*)d_out);
  }
}

// Round 12
// 2073.528 us; speedup vs baseline: 2.0754x; 1.0017x over previous
//
#include <hip/hip_runtime.h>
#include <stdint.h>

typedef unsigned int u32;
typedef unsigned short u16;
typedef unsigned char u8;
typedef __attribute__((ext_vector_type(8))) short s8v;
typedef __attribute__((ext_vector_type(8))) __bf16 bf16x8;
typedef __attribute__((ext_vector_type(4))) float f32x4;

// ---------------- workspace layout (bytes) ----------------
#define OFF_HENC 0ull                 // [16][96][256][128] bf16 (raw h, pre-LN)
#define OFF_M    100663296ull         // [16][96][256][128] bf16 (intermediate)
#define OFF_MI8  201326592ull         // [1536][256][128] u8   (50331648)
#define OFF_MSCL 251658240ull         // [1536][256] f32       (1572864)
#define OFF_APF  253231104ull         // [4][96][96] f32
#define OFF_APB  253378560ull         // [4][96][96] bf16
#define OFF_WNF  253452288ull         // [8*5][64][8] bf16
#define OFF_WSF  253493248ull         // [8*5][64][8] bf16
#define OFF_KWF  253534208ull         // [8*4][64][8] bf16
#define OFF_VWF  253566976ull         // [8*4][64][8] bf16
#define OFF_WIHF 253599744ull         // [24*4][64][8] bf16
#define OFF_WHHF 253698048ull         // [24*4][64][8] bf16
#define OFF_CWY  253796352ull         // [384][4] f32
#define OFF_UPAD 253802496ull         // [256][32] bf16
#define OFF_SCAL 253818880ull         // scal[0]=1/sigma, scal[1]=exp(log_tau)
#define OFF_HH   253819136ull         // [1536][128] f32 head hidden state
#define OFF_Y    254605568ull         // 2 x [1536][4] f32 ping-pong y

__device__ __forceinline__ u16 f2bf(float f) {
  u32 u = __float_as_uint(f);
  u32 r = u + 0x7fffu + ((u >> 16) & 1u);
  return (u16)(r >> 16);
}
__device__ __forceinline__ float bf2f(u16 h) { return __uint_as_float(((u32)h) << 16); }
__device__ __forceinline__ float blo(u32 u) { return __uint_as_float(u << 16); }
__device__ __forceinline__ float bhi(u32 u) { return __uint_as_float(u & 0xffff0000u); }
__device__ __forceinline__ float sigm(float x) { return 1.f / (1.f + __expf(-x)); }
__device__ __forceinline__ float tanh_f(float x) {
  float a = fminf(fabsf(x), 15.f);
  float e = __expf(2.f * a);
  float t = (e - 1.f) / (e + 1.f);
  return copysignf(t, x);
}
__device__ __forceinline__ f32x4 MFMA(s8v a, s8v b, f32x4 c) {
  return __builtin_amdgcn_mfma_f32_16x16x32_bf16(
      __builtin_bit_cast(bf16x8, a), __builtin_bit_cast(bf16x8, b), c, 0, 0, 0);
}
__device__ __forceinline__ float ub0(u32 x) { return (float)(x & 0xffu); }
__device__ __forceinline__ float ub1(u32 x) { return (float)((x >> 8) & 0xffu); }
__device__ __forceinline__ float ub2(u32 x) { return (float)((x >> 16) & 0xffu); }
__device__ __forceinline__ float ub3(u32 x) { return (float)((x >> 24) & 0xffu); }

// barrier that waits only on LDS ops (keeps global stores in flight)
#define LGKM_BARRIER()                                        \
  do {                                                        \
    asm volatile("s_waitcnt lgkmcnt(0)" ::: "memory");        \
    __builtin_amdgcn_s_barrier();                             \
  } while (0)

// =====================================================================
// K0a: phase-adjacency (per p), spectral norm sigma, tpos table, cWy
// =====================================================================
__global__ void k0a(const float* __restrict__ S, const float* __restrict__ G,
                    const float* __restrict__ Wn, const float* __restrict__ snu,
                    const float* __restrict__ logtau, const float* __restrict__ tpw,
                    const float* __restrict__ tpb, const float* __restrict__ cWih,
                    float* __restrict__ Apf, u16* __restrict__ Apb,
                    float* __restrict__ scal, u16* __restrict__ upad,
                    float* __restrict__ cWy) {
  int tid = threadIdx.x;
  int blk = blockIdx.x;
  if (blk < 4) {
    int p = blk;
    __shared__ float gg[96];
    __shared__ float gfac;
    if (tid < 96) {
      float x = G[p * 96 + tid];
      float sp = fmaxf(x, 0.f) + log1pf(__expf(-fabsf(x)));
      gg[tid] = sp + 1e-6f;
    }
    __syncthreads();
    if (tid == 0) {
      float s = 0;
      for (int i = 0; i < 96; ++i) s += gg[i];
      gfac = 96.f / fmaxf(s, 1e-6f);
    }
    __syncthreads();
    if (tid < 96) {
      int i = tid;
      const float* srow = S + ((size_t)p * 96 + i) * 96;
      float den = 0;
      for (int j = 0; j < 96; ++j) { float v = (j == i) ? 0.f : srow[j]; den += fabsf(v); }
      den = fmaxf(den, 1e-6f);
      float sc = gg[i] * gfac / den;
      for (int j = 0; j < 96; ++j) {
        float v = (j == i) ? 0.f : srow[j];
        float a = v * sc;
        Apf[((size_t)p * 96 + i) * 96 + j] = a;
        Apb[((size_t)p * 96 + i) * 96 + j] = f2bf(a);
      }
    }
  } else if (blk == 4) {
    __shared__ float sv[144];
    __shared__ float su[128];
    __shared__ float snorm;
    if (tid < 144) {
      float a = 0;
      for (int d = 0; d < 128; ++d) a += Wn[d * 144 + tid] * snu[d];
      sv[tid] = a;
    }
    __syncthreads();
    if (tid == 0) {
      float s = 0;
      for (int j = 0; j < 144; ++j) s += sv[j] * sv[j];
      snorm = sqrtf(s) + 1e-12f;
    }
    __syncthreads();
    if (tid < 144) sv[tid] = sv[tid] / snorm;
    __syncthreads();
    if (tid < 128) {
      float a = 0;
      for (int j = 0; j < 144; ++j) a += Wn[tid * 144 + j] * sv[j];
      su[tid] = a;
    }
    __syncthreads();
    if (tid == 0) {
      float ss = 0;
      for (int d = 0; d < 128; ++d) ss += su[d] * su[d];
      float nu = sqrtf(ss);
      float sigma = ss / (nu + 1e-12f);
      scal[0] = 1.f / sigma;
      scal[1] = __expf(logtau[0]);
    }
  } else {
    for (int idx = tid; idx < 256 * 32; idx += 256) {
      int t = idx >> 5, kk = idx & 31;
      float v = 0.f;
      if (kk < 16) v = tanh_f((float)t * (1.f / 255.f) * tpw[kk] + tpb[kk]);
      upad[idx] = f2bf(v);
    }
    for (int idx = tid; idx < 1536; idx += 256)
      cWy[idx] = cWih[(idx >> 2) * 132 + 128 + (idx & 3)];
  }
}

// =====================================================================
// K0b: pack all B-operand fragment arrays
// =====================================================================
__global__ void k0b(const float* __restrict__ Wn, const float* __restrict__ Ws,
                    const float* __restrict__ kw, const float* __restrict__ vw,
                    const float* __restrict__ cWih, const float* __restrict__ cWhh,
                    const float* __restrict__ scal,
                    u16* __restrict__ WnF, u16* __restrict__ WsF,
                    u16* __restrict__ kwF, u16* __restrict__ vwF,
                    u16* __restrict__ wiF, u16* __restrict__ whF) {
  int idx = blockIdx.x * 256 + threadIdx.x;
  int lane, j, ctkq, ct, kq, col, k;
  if (idx < 20480) {
    ctkq = idx >> 9; lane = (idx >> 3) & 63; j = idx & 7;
    ct = ctkq / 5; kq = ctkq % 5;
    col = ct * 16 + (lane & 15); k = kq * 32 + ((lane >> 4) << 3) + j;
    float v = (k < 144) ? Wn[col * 144 + k] * scal[0] : 0.f;
    WnF[idx] = f2bf(v);
    return;
  }
  idx -= 20480;
  if (idx < 20480) {
    ctkq = idx >> 9; lane = (idx >> 3) & 63; j = idx & 7;
    ct = ctkq / 5; kq = ctkq % 5;
    col = ct * 16 + (lane & 15); k = kq * 32 + ((lane >> 4) << 3) + j;
    float v = (k < 144) ? Ws[col * 144 + k] : 0.f;
    WsF[idx] = f2bf(v);
    return;
  }
  idx -= 20480;
  if (idx < 16384) {
    ctkq = idx >> 9; lane = (idx >> 3) & 63; j = idx & 7;
    ct = ctkq >> 2; kq = ctkq & 3;
    col = ct * 16 + (lane & 15); k = kq * 32 + ((lane >> 4) << 3) + j;
    kwF[idx] = f2bf(kw[k * 128 + col]);
    return;
  }
  idx -= 16384;
  if (idx < 16384) {
    ctkq = idx >> 9; lane = (idx >> 3) & 63; j = idx & 7;
    ct = ctkq >> 2; kq = ctkq & 3;
    col = ct * 16 + (lane & 15); k = kq * 32 + ((lane >> 4) << 3) + j;
    vwF[idx] = f2bf(vw[col * 128 + k]);
    return;
  }
  idx -= 16384;
  if (idx < 49152) {
    ctkq = idx >> 9; lane = (idx >> 3) & 63; j = idx & 7;
    ct = ctkq >> 2; kq = ctkq & 3;
    col = ct * 16 + (lane & 15); k = kq * 32 + ((lane >> 4) << 3) + j;
    wiF[idx] = f2bf(cWih[col * 132 + k]);
    return;
  }
  idx -= 49152;
  if (idx < 49152) {
    ctkq = idx >> 9; lane = (idx >> 3) & 63; j = idx & 7;
    ct = ctkq >> 2; kq = ctkq & 3;
    col = ct * 16 + (lane & 15); k = kq * 32 + ((lane >> 4) << 3) + j;
    whF[idx] = f2bf(cWhh[col * 128 + k]);
  }
}

// =====================================================================
// K1: GRU encode, LN deferred to k3. One block per n, 8 waves.
// In-loop barrier waits ONLY on lgkmcnt: the per-step Henc global
// stores stay in flight instead of being drained by __syncthreads'
// implicit vmcnt(0) every step (they retire in the background).
// =====================================================================
__launch_bounds__(512)
__global__ void k1_encode(const float* __restrict__ X, const float* __restrict__ Wih,
                          const float* __restrict__ Whh, const float* __restrict__ bih,
                          const float* __restrict__ bhh, u16* __restrict__ Henc) {
  const int n = blockIdx.x;
  const int lane = threadIdx.x & 63, w = threadIdx.x >> 6;
  const int colt = lane & 15, grp = lane >> 4;
  __shared__ __align__(16) float Xl[16][256][4];
  __shared__ __align__(16) u16 hb[2][16][136];

  for (int idx = threadIdx.x; idx < 16 * 1024; idx += 512) {
    int b = idx >> 10, rem = idx & 1023, c = rem >> 8, t = rem & 255;
    Xl[b][t][c] = X[(((size_t)b * 96 + n) * 4 + c) * 256 + t];
  }
  for (int idx = threadIdx.x; idx < 2 * 16 * 136; idx += 512) (&hb[0][0][0])[idx] = 0;

  s8v bfr[3][4];
#pragma unroll
  for (int g = 0; g < 3; ++g) {
    int col = g * 128 + w * 16 + colt;
    const float* wr = Whh + ((size_t)n * 384 + col) * 128;
#pragma unroll
    for (int kq = 0; kq < 4; ++kq) {
      int k0 = kq * 32 + grp * 8;
      float4 f0 = *(const float4*)(wr + k0);
      float4 f1 = *(const float4*)(wr + k0 + 4);
      union { s8v v; u16 s[8]; } tmp;
      tmp.s[0] = f2bf(f0.x); tmp.s[1] = f2bf(f0.y); tmp.s[2] = f2bf(f0.z); tmp.s[3] = f2bf(f0.w);
      tmp.s[4] = f2bf(f1.x); tmp.s[5] = f2bf(f1.y); tmp.s[6] = f2bf(f1.z); tmp.s[7] = f2bf(f1.w);
      bfr[g][kq] = tmp.v;
    }
  }
  float wihr[3][4], bi[3], bh[3];
#pragma unroll
  for (int g = 0; g < 3; ++g) {
    int col = g * 128 + w * 16 + colt;
    float4 wv = *(const float4*)(Wih + ((size_t)n * 384 + col) * 4);
    wihr[g][0] = wv.x; wihr[g][1] = wv.y; wihr[g][2] = wv.z; wihr[g][3] = wv.w;
    bi[g] = bih[n * 384 + col];
    bh[g] = bhh[n * 384 + col];
  }
  float h_reg[4] = {0.f, 0.f, 0.f, 0.f};
  __syncthreads();

  int cur = 0;
  for (int t = 0; t < 256; ++t) {
    s8v a[4];
#pragma unroll
    for (int kq = 0; kq < 4; ++kq)
      a[kq] = *(const s8v*)(const void*)&hb[cur][colt][kq * 32 + grp * 8];
    f32x4 acc0 = {0.f, 0.f, 0.f, 0.f}, acc1 = acc0, acc2 = acc0;
#pragma unroll
    for (int kq = 0; kq < 4; ++kq) {
      acc0 = MFMA(a[kq], bfr[0][kq], acc0);
      acc1 = MFMA(a[kq], bfr[1][kq], acc1);
      acc2 = MFMA(a[kq], bfr[2][kq], acc2);
    }
#pragma unroll
    for (int r = 0; r < 4; ++r) {
      int b = grp * 4 + r;
      float4 x4 = *(const float4*)&Xl[b][t][0];
      float gir = bi[0] + x4.x * wihr[0][0] + x4.y * wihr[0][1] + x4.z * wihr[0][2] + x4.w * wihr[0][3];
      float giz = bi[1] + x4.x * wihr[1][0] + x4.y * wihr[1][1] + x4.z * wihr[1][2] + x4.w * wihr[1][3];
      float gin = bi[2] + x4.x * wihr[2][0] + x4.y * wihr[2][1] + x4.z * wihr[2][2] + x4.w * wihr[2][3];
      float rr = sigm(gir + acc0[r] + bh[0]);
      float zz = sigm(giz + acc1[r] + bh[1]);
      float nn = tanh_f(gin + rr * (acc2[r] + bh[2]));
      float hv = (1.f - zz) * nn + zz * h_reg[r];
      h_reg[r] = hv;
      u16 hvb = f2bf(hv);
      Henc[(((size_t)b * 96 + n) * 256 + t) * 128 + w * 16 + colt] = hvb;
      hb[cur ^ 1][b][w * 16 + colt] = hvb;
    }
    LGKM_BARRIER();
    cur ^= 1;
  }
}

// =====================================================================
// K3: per (b,t): LN -> Hc, Hn = Wsn@Hc, Zn = A@Hn, Hs = Wself@Hc,
// Z = leaky(Hs+Zn) -> M (bf16); at t=255 also h0 -> hh.
// =====================================================================
__launch_bounds__(256, 2)
__global__ void k3_mix(const u16* __restrict__ Henc, const u16* __restrict__ upad,
                       const u16* __restrict__ Apb, const int* __restrict__ phases,
                       const float* __restrict__ lng, const float* __restrict__ lnb,
                       const s8v* __restrict__ WnF, const s8v* __restrict__ WsF,
                       u16* __restrict__ M, float* __restrict__ hh) {
  const int b = blockIdx.x >> 8, t = blockIdx.x & 255;
  const int p = phases[b];
  const int lane = threadIdx.x & 63, w = threadIdx.x >> 6;
  const int colt = lane & 15, grp = lane >> 4;
  __shared__ __align__(16) u16 Hc[96][168];
  __shared__ __align__(16) u16 HnT[128][104];
  __shared__ float lnG[128], lnB[128];

  const u16* src = Henc + ((size_t)b * 96 * 256 + t) * 128;
  for (int u = threadIdx.x; u < 96 * 16; u += 256) {
    int j = u >> 4, ch = u & 15;
    *(uint4*)&Hc[j][ch * 8] = *(const uint4*)(src + (size_t)j * 256 * 128 + ch * 8);
  }
  for (int u = threadIdx.x; u < 96 * 16; u += 256) {
    int j = u >> 4, ch = u & 15;
    *(u32*)&Hc[j][128 + ch * 2] = *(const u32*)(upad + t * 32 + ch * 2);
  }
  if (threadIdx.x < 128) {
    lnG[threadIdx.x] = lng[threadIdx.x];
    lnB[threadIdx.x] = lnb[threadIdx.x];
  }
  __syncthreads();
  if (threadIdx.x < 96) {
    int j = threadIdx.x;
    float s = 0.f, q = 0.f;
#pragma unroll 4
    for (int d = 0; d < 128; ++d) {
      float v = bf2f(Hc[j][d]);
      s += v; q += v * v;
    }
    float mu = s * (1.f / 128.f);
    float var = q * (1.f / 128.f) - mu * mu;
    float rs = rsqrtf(var + 1e-5f);
#pragma unroll 4
    for (int d = 0; d < 128; ++d) {
      float v = bf2f(Hc[j][d]);
      Hc[j][d] = f2bf((v - mu) * rs * lnG[d] + lnB[d]);
    }
  }
  __syncthreads();
  for (int jj = 0; jj < 12; ++jj) {
    int job = w * 12 + jj;
    int jt = job >> 3, ct = job & 7;
    f32x4 acc = {0.f, 0.f, 0.f, 0.f};
#pragma unroll
    for (int kq = 0; kq < 5; ++kq) {
      s8v a = *(const s8v*)(const void*)&Hc[jt * 16 + colt][kq * 32 + grp * 8];
      acc = MFMA(a, WnF[(ct * 5 + kq) * 64 + lane], acc);
    }
    int d = ct * 16 + colt, j0 = jt * 16 + grp * 4;
    u32 w0 = ((u32)f2bf(acc[1]) << 16) | f2bf(acc[0]);
    u32 w1 = ((u32)f2bf(acc[3]) << 16) | f2bf(acc[2]);
    *(u32*)&HnT[d][j0] = w0;
    *(u32*)&HnT[d][j0 + 2] = w1;
  }
  __syncthreads();
  for (int jj = 0; jj < 12; ++jj) {
    int job = w * 12 + jj;
    int it = job >> 3, ct = job & 7;
    f32x4 accZ = {0.f, 0.f, 0.f, 0.f}, accS = accZ;
#pragma unroll
    for (int kq = 0; kq < 3; ++kq) {
      s8v a = *(const s8v*)(const void*)(Apb + ((size_t)p * 96 + it * 16 + colt) * 96 + kq * 32 + grp * 8);
      s8v bb = *(const s8v*)(const void*)&HnT[ct * 16 + colt][kq * 32 + grp * 8];
      accZ = MFMA(a, bb, accZ);
    }
#pragma unroll
    for (int kq = 0; kq < 5; ++kq) {
      s8v a = *(const s8v*)(const void*)&Hc[it * 16 + colt][kq * 32 + grp * 8];
      accS = MFMA(a, WsF[(ct * 5 + kq) * 64 + lane], accS);
    }
    int d = ct * 16 + colt;
#pragma unroll
    for (int r = 0; r < 4; ++r) {
      int i = it * 16 + grp * 4 + r;
      float z = accS[r] + accZ[r];
      z = z >= 0.f ? z : 0.1f * z;
      M[(((size_t)b * 96 + i) * 256 + t) * 128 + d] = f2bf(z);
      if (t == 255) hh[((size_t)b * 96 + i) * 128 + d] = z;
    }
  }
}

// =====================================================================
// K3b: quantize M bf16 -> int8 row-scaled. Block = m (1536), thread = t.
// =====================================================================
__launch_bounds__(256)
__global__ void k3b(const u16* __restrict__ Mbf, u8* __restrict__ Mi8,
                    float* __restrict__ Mscl) {
  const size_t m = blockIdx.x;
  const int t = threadIdx.x;
  const u16* src = Mbf + (m * 256 + t) * 128;
  float vals[128];
  float mx = 0.f;
#pragma unroll 8
  for (int d = 0; d < 128; ++d) {
    float f = bf2f(src[d]);
    vals[d] = f;
    mx = fmaxf(mx, fabsf(f));
  }
  float scale = mx * (1.f / 127.f);
  float inv = (mx > 0.f) ? (127.f / mx) : 0.f;
  u32* dst = (u32*)(Mi8 + (m * 256 + t) * 128);
#pragma unroll 8
  for (int dw = 0; dw < 32; ++dw) {
    u32 packed = 0;
#pragma unroll
    for (int j = 0; j < 4; ++j) {
      int q = (int)rintf(vals[dw * 4 + j] * inv) + 128;
      packed |= ((u32)(q & 0xff)) << (8 * j);
    }
    dst[dw] = packed;
  }
  Mscl[m * 256 + t] = scale;
}

// =====================================================================
// K4: one head step (64 launches). 256 blocks x 8 waves; block owns 6 m.
// Phase C: batch-load 16 int8 row-tiles (uint2) + row scales, two-pass
// softmax + weighted sum with the exact bias-correction trick.
// =====================================================================
__launch_bounds__(512)
__global__ void k4_step(int k, const u8* __restrict__ Mi8, const float* __restrict__ Mscl,
                        float* __restrict__ hh,
                        const float* __restrict__ yin, float* __restrict__ yout,
                        const float* __restrict__ Apf, const int* __restrict__ phases,
                        const float* __restrict__ scal,
                        const s8v* __restrict__ kwF, const s8v* __restrict__ vwF,
                        const s8v* __restrict__ wiF, const s8v* __restrict__ whF,
                        const float* __restrict__ cWy, const float* __restrict__ cbih,
                        const float* __restrict__ cbhh, const float* __restrict__ rw,
                        const float* __restrict__ rb, const float* __restrict__ X,
                        float* __restrict__ out) {
  const int bl = blockIdx.x;
  const int b = bl >> 4, n0 = (bl & 15) * 6, m0 = b * 96 + n0;
  const int lane = threadIdx.x & 63, w = threadIdx.x >> 6;
  const int colt = lane & 15, grp = lane >> 4;
  __shared__ float hfl[6][128];
  __shared__ __align__(16) u16 hb[16][136];
  __shared__ __align__(16) u16 qb[6][128];
  __shared__ __align__(16) u16 sb[16][136];
  __shared__ __align__(16) u16 cxb[16][136];
  __shared__ __align__(16) float macc[6][16][128];
  __shared__ float mmd[6][16][4];
  __shared__ float sclL[6][256];
  __shared__ float gi_l[6][392];
  __shared__ float gh_l[6][392];
  __shared__ float ypl[6][4];
  const float scale = scal[1];

  // phase A: load h (rows 0..5), zero pad rows; stage row scales; y-prop
  for (int idx = threadIdx.x; idx < 2048; idx += 512) {
    int i = idx >> 7, d = idx & 127;
    float hv = 0.f;
    if (i < 6) {
      hv = hh[(size_t)(m0 + i) * 128 + d];
      hfl[i][d] = hv;
    } else {
      sb[i][d] = 0;
      cxb[i][d] = 0;
    }
    hb[i][d] = f2bf(hv);
  }
  for (int idx = threadIdx.x; idx < 1536; idx += 512) {
    int mi = idx >> 8, t = idx & 255;
    sclL[mi][t] = Mscl[(size_t)(m0 + mi) * 256 + t];
  }
  if (w < 6) {
    int i = w, ni = n0 + w;
    const float* arow = Apf + ((size_t)phases[b] * 96 + ni) * 96;
    float acc[4] = {0.f, 0.f, 0.f, 0.f};
    for (int j = lane; j < 96; j += 64) {
      float av = arow[j];
      const float* yr = yin + ((size_t)b * 96 + j) * 4;
      acc[0] += av * yr[0]; acc[1] += av * yr[1];
      acc[2] += av * yr[2]; acc[3] += av * yr[3];
    }
#pragma unroll
    for (int mm = 1; mm < 64; mm <<= 1) {
#pragma unroll
      for (int c = 0; c < 4; ++c) acc[c] += __shfl_xor(acc[c], mm);
    }
    if (lane < 4) ypl[i][lane] = yin[((size_t)b * 96 + ni) * 4 + lane] + 0.3f * acc[lane];
  }
  __syncthreads();

  // phase B: q = h @ k_w (scale folded in)
  {
    int ct = w;
    f32x4 acc = {0.f, 0.f, 0.f, 0.f};
#pragma unroll
    for (int kq = 0; kq < 4; ++kq) {
      s8v a = *(const s8v*)(const void*)&hb[colt][kq * 32 + grp * 8];
      acc = MFMA(a, kwF[(ct * 4 + kq) * 64 + lane], acc);
    }
#pragma unroll
    for (int r = 0; r < 4; ++r) {
      int i = grp * 4 + r;
      if (i < 6) qb[i][ct * 16 + colt] = f2bf(acc[r] * scale);
    }
  }
  __syncthreads();

  // phase C: int8 scores+softmax+weighted-sum, single pass over Mi8.
#pragma unroll 1
  for (int uu = 0; uu < 3; ++uu) {
    int u = w + uu * 8;
    int mi = u >> 2, qq = u & 3;
    float qf[8];
    const u32* qsrc = (const u32*)&qb[mi][colt * 8];
#pragma unroll
    for (int x = 0; x < 4; ++x) { u32 v = qsrc[x]; qf[2 * x] = blo(v); qf[2 * x + 1] = bhi(v); }
    float qs = qf[0] + qf[1] + qf[2] + qf[3] + qf[4] + qf[5] + qf[6] + qf[7];
    qs += __shfl_xor(qs, 1); qs += __shfl_xor(qs, 2);
    qs += __shfl_xor(qs, 4); qs += __shfl_xor(qs, 8);
    const u8* mp = Mi8 + ((size_t)(m0 + mi) * 256 + qq * 64 + grp) * 128 + colt * 8;
    uint2 mv[16];
#pragma unroll
    for (int it = 0; it < 16; ++it) mv[it] = *(const uint2*)(mp + (size_t)it * 512);
    float scl[16];
#pragma unroll
    for (int it = 0; it < 16; ++it) scl[it] = sclL[mi][qq * 64 + it * 4 + grp];
    float p[16];
#pragma unroll
    for (int it = 0; it < 16; ++it) {
      uint2 v = mv[it];
      float pp = qf[0] * ub0(v.x) + qf[1] * ub1(v.x) + qf[2] * ub2(v.x) + qf[3] * ub3(v.x)
               + qf[4] * ub0(v.y) + qf[5] * ub1(v.y) + qf[6] * ub2(v.y) + qf[7] * ub3(v.y);
      pp += __shfl_xor(pp, 1); pp += __shfl_xor(pp, 2);
      pp += __shfl_xor(pp, 4); pp += __shfl_xor(pp, 8);
      p[it] = scl[it] * (pp - 128.f * qs);
    }
    float mx = p[0];
#pragma unroll
    for (int it = 1; it < 16; ++it) mx = fmaxf(mx, p[it]);
    float den = 0.f, gs = 0.f;
    float acc[8] = {0.f, 0.f, 0.f, 0.f, 0.f, 0.f, 0.f, 0.f};
#pragma unroll
    for (int it = 0; it < 16; ++it) {
      float wgt = __expf(p[it] - mx);
      den += wgt;
      float g = wgt * scl[it];
      gs += g;
      uint2 v = mv[it];
      acc[0] += g * ub0(v.x); acc[1] += g * ub1(v.x);
      acc[2] += g * ub2(v.x); acc[3] += g * ub3(v.x);
      acc[4] += g * ub0(v.y); acc[5] += g * ub1(v.y);
      acc[6] += g * ub2(v.y); acc[7] += g * ub3(v.y);
    }
    int su = qq * 4 + grp;
    float* dst = &macc[mi][su][colt * 8];
#pragma unroll
    for (int j = 0; j < 8; ++j) dst[j] = acc[j];
    if (colt == 0) { mmd[mi][su][0] = mx; mmd[mi][su][1] = den; mmd[mi][su][2] = gs; }
  }
  __syncthreads();

  // phase C-merge: combine 16 sub-units per m -> sb (bf16)
  if (w < 6) {
    int i = w;
    float MX = -3.0e38f;
#pragma unroll
    for (int uy = 0; uy < 16; ++uy) MX = fmaxf(MX, mmd[i][uy][0]);
    float DEN = 0.f, GS = 0.f, s0 = 0.f, s1 = 0.f;
    int c0 = lane * 2;
#pragma unroll
    for (int uy = 0; uy < 16; ++uy) {
      float fac = __expf(mmd[i][uy][0] - MX);
      DEN += fac * mmd[i][uy][1];
      GS += fac * mmd[i][uy][2];
      s0 += fac * macc[i][uy][c0];
      s1 += fac * macc[i][uy][c0 + 1];
    }
    float rden = 1.f / DEN;
    float corr = 128.f * GS;
    *(u32*)&sb[i][c0] = ((u32)f2bf((s1 - corr) * rden) << 16) | f2bf((s0 - corr) * rden);
  }
  __syncthreads();

  // phase D: ctx = s @ v_w^T
  {
    int ct = w;
    f32x4 acc = {0.f, 0.f, 0.f, 0.f};
#pragma unroll
    for (int kq = 0; kq < 4; ++kq) {
      s8v a = *(const s8v*)(const void*)&sb[colt][kq * 32 + grp * 8];
      acc = MFMA(a, vwF[(ct * 4 + kq) * 64 + lane], acc);
    }
#pragma unroll
    for (int r = 0; r < 4; ++r) {
      int i = grp * 4 + r;
      if (i < 6) cxb[i][ct * 16 + colt] = f2bf(acc[r]);
    }
  }
  __syncthreads();

  // phase E: cell gates gi (ctx part) and gh
  for (int jj = 0; jj < 6; ++jj) {
    int job = w * 6 + jj;
    int gsel = (job >= 24) ? 1 : 0;
    int ct = job - gsel * 24;
    const u16(*asrc)[136] = gsel ? hb : cxb;
    const s8v* wf = gsel ? whF : wiF;
    f32x4 acc = {0.f, 0.f, 0.f, 0.f};
#pragma unroll
    for (int kq = 0; kq < 4; ++kq) {
      s8v a = *(const s8v*)(const void*)&asrc[colt][kq * 32 + grp * 8];
      acc = MFMA(a, wf[(ct * 4 + kq) * 64 + lane], acc);
    }
    float* dst = gsel ? &gh_l[0][0] : &gi_l[0][0];
#pragma unroll
    for (int r = 0; r < 4; ++r) {
      int i = grp * 4 + r;
      if (i < 6) dst[i * 392 + ct * 16 + colt] = acc[r];
    }
  }
  __syncthreads();

  // phase F: GRU update + y_t + outputs
  if (w < 6) {
    int i = w, m = m0 + i;
    float yp0 = ypl[i][0], yp1 = ypl[i][1], yp2 = ypl[i][2], yp3 = ypl[i][3];
    float hn2[2];
#pragma unroll
    for (int q = 0; q < 2; ++q) {
      int d = lane + q * 64;
      float gir = gi_l[i][d] + cbih[d];
      float giz = gi_l[i][d + 128] + cbih[d + 128];
      float gin = gi_l[i][d + 256] + cbih[d + 256];
      const float* wy0 = cWy + (size_t)d * 4;
      const float* wy1 = cWy + (size_t)(d + 128) * 4;
      const float* wy2 = cWy + (size_t)(d + 256) * 4;
      gir += yp0 * wy0[0] + yp1 * wy0[1] + yp2 * wy0[2] + yp3 * wy0[3];
      giz += yp0 * wy1[0] + yp1 * wy1[1] + yp2 * wy1[2] + yp3 * wy1[3];
      gin += yp0 * wy2[0] + yp1 * wy2[1] + yp2 * wy2[2] + yp3 * wy2[3];
      float ghr = gh_l[i][d] + cbhh[d];
      float ghz = gh_l[i][d + 128] + cbhh[d + 128];
      float ghn = gh_l[i][d + 256] + cbhh[d + 256];
      float rr = sigm(gir + ghr);
      float zz = sigm(giz + ghz);
      float nn = tanh_f(gin + rr * ghn);
      float hv = (1.f - zz) * nn + zz * hfl[i][d];
      hh[(size_t)m * 128 + d] = hv;
      hn2[q] = hv;
    }
    float p0 = hn2[0] * rw[0 * 128 + lane] + hn2[1] * rw[0 * 128 + lane + 64];
    float p1 = hn2[0] * rw[1 * 128 + lane] + hn2[1] * rw[1 * 128 + lane + 64];
    float p2 = hn2[0] * rw[2 * 128 + lane] + hn2[1] * rw[2 * 128 + lane + 64];
    float p3 = hn2[0] * rw[3 * 128 + lane] + hn2[1] * rw[3 * 128 + lane + 64];
#pragma unroll
    for (int mm = 1; mm < 64; mm <<= 1) {
      p0 += __shfl_xor(p0, mm); p1 += __shfl_xor(p1, mm);
      p2 += __shfl_xor(p2, mm); p3 += __shfl_xor(p3, mm);
    }
    if (lane < 4) {
      int c = lane;
      float pv = (c == 0) ? p0 : (c == 1) ? p1 : (c == 2) ? p2 : p3;
      float ypc = (c == 0) ? yp0 : (c == 1) ? yp1 : (c == 2) ? yp2 : yp3;
      float yv = pv + rb[c] + ypc;
      yout[(size_t)m * 4 + c] = yv;
      float xl = X[((size_t)m * 4 + c) * 256 + 255];
      float Yh = xl + yv;
      out[((size_t)m * 4 + c) * 64 + k] = Yh;
      if (k == 0) out[393216 + (size_t)m * 4 + c] = Yh;
    }
  }
}

// =====================================================================
extern "C" void kernel_launch(void* const* d_in, const int* in_sizes, int n_in,
                              void* d_out, int out_size, void* d_ws, size_t ws_size,
                              hipStream_t stream) {
  const float* X      = (const float*)d_in[0];
  const int*   phases = (const int*)d_in[1];
  const float* Wih    = (const float*)d_in[2];
  const float* Whh    = (const float*)d_in[3];
  const float* bih    = (const float*)d_in[4];
  const float* bhh    = (const float*)d_in[5];
  const float* lng    = (const float*)d_in[6];
  const float* lnb    = (const float*)d_in[7];
  const float* tpw    = (const float*)d_in[8];
  const float* tpb    = (const float*)d_in[9];
  const float* S      = (const float*)d_in[10];
  const float* G      = (const float*)d_in[11];
  const float* Wself  = (const float*)d_in[12];
  const float* Wneigh = (const float*)d_in[13];
  const float* snu    = (const float*)d_in[14];
  const float* kw     = (const float*)d_in[15];
  const float* vw     = (const float*)d_in[16];
  const float* cWih   = (const float*)d_in[17];
  const float* cWhh   = (const float*)d_in[18];
  const float* cbih   = (const float*)d_in[19];
  const float* cbhh   = (const float*)d_in[20];
  const float* rw     = (const float*)d_in[21];
  const float* rb     = (const float*)d_in[22];
  const float* ltau   = (const float*)d_in[23];

  char* ws = (char*)d_ws;
  u16*   Henc = (u16*)(ws + OFF_HENC);
  u16*   Mb   = (u16*)(ws + OFF_M);
  u8*    Mi8  = (u8*)(ws + OFF_MI8);
  float* Mscl = (float*)(ws + OFF_MSCL);
  float* Apf  = (float*)(ws + OFF_APF);
  u16*   Apb  = (u16*)(ws + OFF_APB);
  u16*   WnF  = (u16*)(ws + OFF_WNF);
  u16*   WsF  = (u16*)(ws + OFF_WSF);
  u16*   kwF  = (u16*)(ws + OFF_KWF);
  u16*   vwF  = (u16*)(ws + OFF_VWF);
  u16*   wiF  = (u16*)(ws + OFF_WIHF);
  u16*   whF  = (u16*)(ws + OFF_WHHF);
  float* cWy  = (float*)(ws + OFF_CWY);
  u16*   upad = (u16*)(ws + OFF_UPAD);
  float* scal = (float*)(ws + OFF_SCAL);
  float* hh   = (float*)(ws + OFF_HH);

  hipMemsetAsync(ws + OFF_Y, 0, 49152, stream);
  hipLaunchKernelGGL(k0a, dim3(6), dim3(256), 0, stream,
                     S, G, Wneigh, snu, ltau, tpw, tpb, cWih, Apf, Apb, scal, upad, cWy);
  hipLaunchKernelGGL(k0b, dim3(672), dim3(256), 0, stream,
                     Wneigh, Wself, kw, vw, cWih, cWhh, scal, WnF, WsF, kwF, vwF, wiF, whF);
  hipLaunchKernelGGL(k1_encode, dim3(96), dim3(512), 0, stream,
                     X, Wih, Whh, bih, bhh, Henc);
  hipLaunchKernelGGL(k3_mix, dim3(4096), dim3(256), 0, stream,
                     Henc, upad, Apb, phases, lng, lnb,
                     (const s8v*)WnF, (const s8v*)WsF, Mb, hh);
  hipLaunchKernelGGL(k3b, dim3(1536), dim3(256), 0, stream, Mb, Mi8, Mscl);
  for (int k = 0; k < 64; ++k) {
    const float* yi = (const float*)(ws + OFF_Y + (size_t)(k & 1) * 24576);
    float*       yo = (float*)(ws + OFF_Y + (size_t)((k + 1) & 1) * 24576);
    hipLaunchKernelGGL(k4_step, dim3(256), dim3(512), 0, stream,
                       k, Mi8, Mscl, hh, yi, yo, Apf, phases, scal,
                       (const s8v*)kwF, (const s8v*)vwF, (const s8v*)wiF, (const s8v*)whF,
                       cWy, cbih, cbhh, rw, rb, X, (float*)d_out);
  }
}